// Round 10
// baseline (354.610 us; speedup 1.0000x reference)
//
#include <hip/hip_runtime.h>
#include <math.h>

#define B_   8
#define L_   2048
#define D_   1024
#define H_   2048
#define NBLK 8             // H_/256 N-tiles in the GEMM
#define CHK  32            // tokens per chunk in pooling pre-pass
#define NCH  (L_ / CHK)    // 64 chunks per batch item
#define BK   64            // fp8: 64 k per tile (same bytes as bf16 BK=32)
#define NK   (D_ / BK)     // 16 K-steps
#define MARGIN  0.5f       // |logit| below this -> exact f32 recompute
#define MAXFLAG 1024
#define BSCALE  16.0f      // W1 pre-scale (exact pow2), undone in epilogue
#define BUNSCALE 0.0625f

typedef __bf16 bf16_t;
typedef float  f32x4_t  __attribute__((ext_vector_type(4)));
typedef int    i32x4_t  __attribute__((ext_vector_type(4)));
typedef long   i64x2_t  __attribute__((ext_vector_type(2)));

// Swizzled fp8 tile images: tile = 256 rows x BK(64) fp8 = 16KB, 64B/row.
// Logical chunk g (16B) of row r holds k = {g*8..g*8+7} CONCAT {32+g*8..32+g*8+7}
// (both ks-halves of lane-slot g), stored at physical chunk g ^ ((r>>1)&3).
// -> k1 frag read is ONE ds_read_b128/lane, 0 conflicts (round-9 verified).
#define TILE_BYTES 16384

__device__ inline int pk4_fp8(float a, float b, float c, float d) {
  int w = __builtin_amdgcn_cvt_pk_fp8_f32(a, b, 0, false);
  w = __builtin_amdgcn_cvt_pk_fp8_f32(c, d, w, true);
  return w;
}

// ---------------------------------------------------------------------------
// K0a (fused): hidden f32 -> Abf fp8 swizzled tiles AND 32-token chunk sums
// ---------------------------------------------------------------------------
__global__ __launch_bounds__(256) void k0a_packA(
    const float* __restrict__ A,      // [16384][1024]
    unsigned char* __restrict__ Abf,  // [64 mt][16 kt] tiles of 16KB
    float* __restrict__ chunkSum)     // [8][NCH][1024]
{
  __shared__ float scratch[256][65];
  const int kt = blockIdx.x;   // 0..15
  const int mt = blockIdx.y;   // 0..63
  const int r  = threadIdx.x;  // 0..255
  const float* src = A + (size_t)(mt * 256 + r) * D_ + kt * BK;
  float v[64];
#pragma unroll
  for (int q = 0; q < 16; ++q) {
    f32x4_t x = *(const f32x4_t*)(src + q * 4);
    v[q*4] = x.x; v[q*4+1] = x.y; v[q*4+2] = x.z; v[q*4+3] = x.w;
  }
  char* dst = (char*)Abf + ((size_t)(mt * 16 + kt)) * TILE_BYTES + r * 64;
#pragma unroll
  for (int g = 0; g < 4; ++g) {
    i32x4_t o;
    o[0] = pk4_fp8(v[g*8+0], v[g*8+1], v[g*8+2], v[g*8+3]);
    o[1] = pk4_fp8(v[g*8+4], v[g*8+5], v[g*8+6], v[g*8+7]);
    o[2] = pk4_fp8(v[32+g*8+0], v[32+g*8+1], v[32+g*8+2], v[32+g*8+3]);
    o[3] = pk4_fp8(v[32+g*8+4], v[32+g*8+5], v[32+g*8+6], v[32+g*8+7]);
    *(i32x4_t*)(dst + ((g ^ ((r >> 1) & 3)) << 4)) = o;
  }
  // chunk sums: tile spans 256 tokens = 8 chunks of 32, 64 dims
#pragma unroll
  for (int q = 0; q < 16; ++q)
    *(f32x4_t*)&scratch[r][q * 4] = *(const f32x4_t*)&v[q * 4];
  __syncthreads();
  const int ch = r >> 5, j2 = r & 31;
#pragma unroll
  for (int half = 0; half < 2; ++half) {
    const int j = j2 + half * 32;
    float s = 0.f;
#pragma unroll
    for (int q = 0; q < 32; ++q) s += scratch[ch * 32 + q][j];
    const int b  = mt >> 3;
    const int cg = (mt & 7) * 8 + ch;
    chunkSum[((size_t)(b * NCH + cg)) * D_ + kt * BK + j] = s;
  }
}

// ---------------------------------------------------------------------------
// K0b: W1 f32 -> Bbf fp8 swizzled tiles (x16 scale); also zeroes flagcnt
// ---------------------------------------------------------------------------
__global__ __launch_bounds__(256) void k0b_packB(
    const float* __restrict__ W1,     // [1024][2048]
    unsigned char* __restrict__ Bbf,  // [8 nt][16 kt] tiles of 16KB
    int* __restrict__ flagcnt)
{
  const int kt = blockIdx.x;   // 0..15
  const int nt = blockIdx.y;   // 0..7
  const int c  = threadIdx.x;  // 0..255
  if (kt == 0 && nt == 0 && c == 0) *flagcnt = 0;
  const float* src = W1 + (size_t)(kt * BK) * H_ + nt * 256 + c;
  float v[64];
#pragma unroll
  for (int j = 0; j < 64; ++j) v[j] = src[(size_t)j * H_] * BSCALE;
  char* dst = (char*)Bbf + ((size_t)(nt * 16 + kt)) * TILE_BYTES + c * 64;
#pragma unroll
  for (int g = 0; g < 4; ++g) {
    i32x4_t o;
    o[0] = pk4_fp8(v[g*8+0], v[g*8+1], v[g*8+2], v[g*8+3]);
    o[1] = pk4_fp8(v[g*8+4], v[g*8+5], v[g*8+6], v[g*8+7]);
    o[2] = pk4_fp8(v[32+g*8+0], v[32+g*8+1], v[32+g*8+2], v[32+g*8+3]);
    o[3] = pk4_fp8(v[32+g*8+4], v[32+g*8+5], v[32+g*8+6], v[32+g*8+7]);
    *(i32x4_t*)(dst + ((g ^ ((c >> 1) & 3)) << 4)) = o;
  }
}

// ---------------------------------------------------------------------------
// K1: fp8-e4m3 GEMM 256x256 tile, BK=64, 8 waves (2Mx4N, wave tile 128x64).
// Ring-2 LDS (2 x 32KB = 64KB -> 2 blocks/CU co-resident), depth-1 prefetch,
// 2 barriers per K-step: barrier1 releases the overwrite target (WAR),
// counted vmcnt(4) + barrier2 makes stage(t) cross-wave visible while
// stage(t+1) stays in flight (never drains to 0 mid-loop).
// Frag read: ONE ds_read_b128/lane (0 conflicts). Epilogue: relu(C/16+b1).W2.
// ---------------------------------------------------------------------------
__global__ __launch_bounds__(512, 4) void k1_gemm(
    const unsigned char* __restrict__ Abf,
    const unsigned char* __restrict__ Bbf,
    const float* __restrict__ b1,
    const float* __restrict__ W2,
    float* __restrict__ partial)    // [16384][NBLK]
{
  extern __shared__ __align__(16) unsigned char lds[];   // 65536 bytes

  const int tid  = threadIdx.x;           // 0..511
  // XCD-bijective swizzle (512 blocks % 8 == 0)
  const int wg   = (blockIdx.x & 7) * 64 + (blockIdx.x >> 3);
  const int mt   = wg >> 3;               // 0..63
  const int nt   = wg & 7;                // 0..7
  const int m0   = mt * 256;
  const int n0   = nt * 256;
  const int lane = tid & 63;
  const int wave = tid >> 6;              // 0..7
  const int wr = wave >> 2, wc = wave & 3;
  const int lr = lane & 15, lk = lane >> 4;

  const char* aT = (const char*)Abf + ((size_t)mt * NK) * TILE_BYTES;
  const char* bT = (const char*)Bbf + ((size_t)nt * NK) * TILE_BYTES;

  f32x4_t acc[8][4];
#pragma unroll
  for (int m = 0; m < 8; ++m)
#pragma unroll
    for (int n = 0; n < 4; ++n)
      acc[m][n] = (f32x4_t){0.f, 0.f, 0.f, 0.f};

  // stage K-step t into ring buffer buf: A tile 16KB then B tile 16KB
  auto stage = [&](int t, int buf) {
    const char* ga = aT + (size_t)t * TILE_BYTES;
    const char* gb = bT + (size_t)t * TILE_BYTES;
    unsigned char* lb = lds + buf * 32768;
#pragma unroll
    for (int j = 0; j < 4; ++j) {
      const int i = j * 512 + tid;        // 0..2047 16B-chunks
      const char* g = (j < 2) ? ga + i * 16 : gb + (i - 1024) * 16;
      __builtin_amdgcn_global_load_lds(
          (const __attribute__((address_space(1))) void*)g,
          (__attribute__((address_space(3))) void*)(lb + i * 16),
          16, 0, 0);
    }
  };

  stage(0, 0);
  for (int t = 0; t < NK; ++t) {
    __builtin_amdgcn_s_barrier();        // WAR: buf[(t+1)&1] free (compute(t-1) reads done)
    if (t + 1 < NK) {
      stage(t + 1, (t + 1) & 1);
      asm volatile("s_waitcnt vmcnt(4)" ::: "memory");   // stage(t) landed (per-wave)
    } else {
      asm volatile("s_waitcnt vmcnt(0)" ::: "memory");
    }
    __builtin_amdgcn_s_barrier();        // all waves' stage(t) shares visible
    asm volatile("" ::: "memory");       // no LDS reads hoist above barrier

    const char* sA = (const char*)(lds + (t & 1) * 32768);
    const char* sB = sA + 16384;
    // one b128 per frag: w.x = ks0 operand (k=lk*8+e), w.y = ks1 (k=32+lk*8+e)
    i64x2_t a[8], b[4];
#pragma unroll
    for (int m = 0; m < 8; ++m) {
      const int r = wr * 128 + m * 16 + lr;
      a[m] = *(const i64x2_t*)(sA + r * 64 + ((lk ^ ((r >> 1) & 3)) << 4));
    }
#pragma unroll
    for (int n = 0; n < 4; ++n) {
      const int c = wc * 64 + n * 16 + lr;
      b[n] = *(const i64x2_t*)(sB + c * 64 + ((lk ^ ((c >> 1) & 3)) << 4));
    }
    __builtin_amdgcn_s_setprio(1);
#pragma unroll
    for (int m = 0; m < 8; ++m)
#pragma unroll
      for (int n = 0; n < 4; ++n)
        acc[m][n] = __builtin_amdgcn_mfma_f32_16x16x32_fp8_fp8(
            a[m].x, b[n].x, acc[m][n], 0, 0, 0);
#pragma unroll
    for (int m = 0; m < 8; ++m)
#pragma unroll
      for (int n = 0; n < 4; ++n)
        acc[m][n] = __builtin_amdgcn_mfma_f32_16x16x32_fp8_fp8(
            a[m].y, b[n].y, acc[m][n], 0, 0, 0);
    __builtin_amdgcn_s_setprio(0);
  }

  // ---- epilogue: relu(C/16 + b1) * W2, reduce over cols, write partial ----
  float rs[8][4];
#pragma unroll
  for (int m = 0; m < 8; ++m)
#pragma unroll
    for (int rg = 0; rg < 4; ++rg) rs[m][rg] = 0.f;

#pragma unroll
  for (int n = 0; n < 4; ++n) {
    const int jg = n0 + wc * 64 + n * 16 + lr;   // C/D: col = lane&15
    const float w2v = W2[jg];
    const float b1v = b1[jg];
#pragma unroll
    for (int m = 0; m < 8; ++m)
#pragma unroll
      for (int rg = 0; rg < 4; ++rg) {
        float v = acc[m][n][rg] * BUNSCALE + b1v;
        rs[m][rg] += fmaxf(v, 0.f) * w2v;
      }
  }
#pragma unroll
  for (int m = 0; m < 8; ++m)
#pragma unroll
    for (int rg = 0; rg < 4; ++rg) {
      float v = rs[m][rg];
      v += __shfl_xor(v, 1);
      v += __shfl_xor(v, 2);
      v += __shfl_xor(v, 4);
      v += __shfl_xor(v, 8);
      rs[m][rg] = v;                      // col-sum of this wave's 64-col slab
    }
  __syncthreads();                        // all frag reads done; alias lds
  float (*part_lds)[4] = (float(*)[4])lds;   // [256][4]
  if (lr == 0) {
#pragma unroll
    for (int m = 0; m < 8; ++m)
#pragma unroll
      for (int rg = 0; rg < 4; ++rg)
        part_lds[wr * 128 + m * 16 + lk * 4 + rg][wc] = rs[m][rg];
  }
  __syncthreads();
  if (tid < 256) {
    const float sum = part_lds[tid][0] + part_lds[tid][1]
                    + part_lds[tid][2] + part_lds[tid][3];
    partial[(size_t)(m0 + tid) * NBLK + nt] = sum;
  }
}

// ---------------------------------------------------------------------------
// K2a: logits[i] = b2 + sum(partial[i][:]); flag near-threshold tokens
// ---------------------------------------------------------------------------
__global__ __launch_bounds__(256) void k2a_logits(
    const float* __restrict__ partial,
    const float* __restrict__ b2,
    float* __restrict__ logits,
    int* __restrict__ flaglist,
    int* __restrict__ flagcnt)
{
  const int i = blockIdx.x * 256 + threadIdx.x;   // 0..16383
  const float* pp = partial + (size_t)i * NBLK;
  float lg = b2[0];
#pragma unroll
  for (int j = 0; j < NBLK; ++j) lg += pp[j];
  logits[i] = lg;
  if (fabsf(lg) < MARGIN) {
    int s = atomicAdd(flagcnt, 1);
    if (s < MAXFLAG) flaglist[s] = i;
  }
}

// ---------------------------------------------------------------------------
// K2b: exact f32 recompute of flagged rows, split 8x by column group.
// grid (8 cg, 64 fslot); partials to fixpart[f][cg] (deterministic).
// ---------------------------------------------------------------------------
__global__ __launch_bounds__(256) void k2b_fixup(
    const float* __restrict__ hidden,
    const float* __restrict__ W1,
    const float* __restrict__ b1,
    const float* __restrict__ W2,
    const int* __restrict__ flaglist,
    const int* __restrict__ flagcnt,
    float* __restrict__ fixpart)         // [MAXFLAG][8]
{
  const int cnt = min(*flagcnt, MAXFLAG);
  const int cg = blockIdx.x;             // 0..7
  __shared__ float hrow[D_];
  __shared__ float red[256];
  const int tid = threadIdx.x;
  const int col = cg * 256 + tid;
  for (int f = blockIdx.y; f < cnt; f += 64) {
    const int i = flaglist[f];
    const float* h = hidden + (size_t)i * D_;
    __syncthreads();
    *(f32x4_t*)&hrow[tid * 4] = *(const f32x4_t*)&h[tid * 4];
    __syncthreads();
    float acc = 0.f;
#pragma unroll 8
    for (int k = 0; k < D_; ++k)
      acc = fmaf(hrow[k], W1[(size_t)k * H_ + col], acc);
    red[tid] = fmaxf(acc + b1[col], 0.f) * W2[col];
    __syncthreads();
    for (int st = 128; st > 0; st >>= 1) {
      if (tid < st) red[tid] += red[tid + st];
      __syncthreads();
    }
    if (tid == 0) fixpart[f * 8 + cg] = red[0];
  }
}

// ---------------------------------------------------------------------------
// K2c: per-batch scan. Prologue applies fixup combine for this batch's
// flagged tokens; then lengths, hb bits, parallel prefix scan, segment
// starts, shortened mask, binomial NLL.
// ---------------------------------------------------------------------------
__global__ __launch_bounds__(256) void k2c_scan(
    float* __restrict__ logits,          // [8][2048] (fixed in-place)
    const float* __restrict__ mask,      // [8][2048]
    const float* __restrict__ target,    // [8]
    const float* __restrict__ b2,
    const float* __restrict__ fixpart,   // [MAXFLAG][8]
    const int* __restrict__ flaglist,
    const int* __restrict__ flagcnt,
    float* __restrict__ outmask,         // [8][2048]
    int*   __restrict__ seg,             // [8][2050]
    float* __restrict__ hdr)             // [8][4]
{
  const int b = blockIdx.x, tid = threadIdx.x;
  __shared__ float redf[256];
  __shared__ int tsum[256];
  __shared__ unsigned char hbs[L_];

  // fix-combine for this batch's flagged tokens (exact f32 logits)
  const int cnt = min(*flagcnt, MAXFLAG);
  for (int f = tid; f < cnt; f += 256) {
    const int i = flaglist[f];
    if ((i >> 11) == b) {
      float s = b2[0];
#pragma unroll
      for (int cg = 0; cg < 8; ++cg) s += fixpart[f * 8 + cg];
      logits[i] = s;
    }
  }
  // length (tree reduce); the first barrier also orders the fixup writes
  float lm = 0.f;
#pragma unroll
  for (int e = 0; e < 8; ++e) lm += mask[b * L_ + tid * 8 + e];
  redf[tid] = lm;
  __syncthreads();
  for (int s = 128; s > 0; s >>= 1) {
    if (tid < s) redf[tid] += redf[tid + s];
    __syncthreads();
  }
  const int length = (int)(redf[0] + 0.5f);

  int hloc[8];
  int lsum = 0;
#pragma unroll
  for (int e = 0; e < 8; ++e) {
    const int t = tid * 8 + e;
    const float lg = logits[b * L_ + t];
    int hb = (lg > 0.f) && (t < length);
    if (length < L_ && t == length - 1) hb = 1;
    hloc[e] = hb;
    hbs[t] = (unsigned char)hb;
    lsum += hb;
  }
  // parallel inclusive scan (Hillis-Steele) over per-thread sums
  tsum[tid] = lsum;
  __syncthreads();
  for (int off = 1; off < 256; off <<= 1) {
    int v = tsum[tid];
    int add = (tid >= off) ? tsum[tid - off] : 0;
    __syncthreads();
    tsum[tid] = v + add;
    __syncthreads();
  }
  const int ktot = tsum[255];

  int pre = tsum[tid] - lsum;            // exclusive prefix
  for (int e = 0; e < 8; ++e) {
    const int t = tid * 8 + e;
    if (t < length) {
      const bool st = (t == 0) || hbs[t - 1];
      if (st) seg[b * 2050 + pre] = t;
    }
    pre += hloc[e];
  }

#pragma unroll
  for (int e = 0; e < 8; ++e) {
    const int t = tid * 8 + e;
    outmask[b * L_ + t] = (t < ktot) ? 1.f : 0.f;
  }

  __syncthreads();
  if (tid == 0) {
    const int maxseg = ktot - (length > 0 ? (int)hbs[length - 1] : 0);
    seg[b * 2050 + maxseg + 1] = length;
    const float n = (float)length, k = (float)ktot;
    float p = target[b] / fmaxf(n, 1.f);
    p = fminf(fmaxf(p, 1e-6f), 1.f - 1e-6f);
    const float lp = lgammaf(n + 1.f) - lgammaf(k + 1.f) - lgammaf(n - k + 1.f)
                   + k * logf(p) + (n - k) * log1pf(-p);
    hdr[b * 4 + 0] = n;
    hdr[b * 4 + 1] = k;
    hdr[b * 4 + 2] = (float)maxseg;
    hdr[b * 4 + 3] = -lp;
  }
}

// ---------------------------------------------------------------------------
// K4b: pooled[b][s][:] = mean(hidden[b][st:en][:]) + PE[s][:]
// segment mean = edge rows + full 32-token chunk sums. Block 0 also emits
// the three scalars.
// ---------------------------------------------------------------------------
__global__ __launch_bounds__(256) void k4b_pool(
    const float* __restrict__ hidden,
    const float* __restrict__ chunkSum,
    const int*   __restrict__ seg,
    const float* __restrict__ hdr,
    float* __restrict__ pooled,
    float* __restrict__ out3)
{
  const int bid = blockIdx.x;
  const int b = bid >> 11, s = bid & 2047;
  const int tid = threadIdx.x;
  if (bid == 0 && tid == 0) {
    float s_lp = 0.f, s_k = 0.f, s_n = 0.f;
    for (int i = 0; i < B_; ++i) {
      s_n  += hdr[i * 4 + 0];
      s_k  += hdr[i * 4 + 1];
      s_lp += hdr[i * 4 + 3];
    }
    out3[0] = 10.f * (s_lp * 0.125f);
    out3[1] = s_k;
    out3[2] = s_n;
  }
  const int maxseg = (int)hdr[b * 4 + 2];

  float a0 = 0.f, a1 = 0.f, a2 = 0.f, a3 = 0.f;
  if (s <= maxseg) {
    const int st = seg[b * 2050 + s];
    const int en = seg[b * 2050 + s + 1];
    const float* hrow = hidden + (size_t)(b * L_) * D_ + tid * 4;
    const float* crow = chunkSum + (size_t)(b * NCH) * D_ + tid * 4;
    const int cs = (st + CHK - 1) / CHK;
    const int ce = en / CHK;
    if (cs >= ce) {
      for (int t = st; t < en; ++t) {
        const f32x4_t v = *(const f32x4_t*)(hrow + (size_t)t * D_);
        a0 += v.x; a1 += v.y; a2 += v.z; a3 += v.w;
      }
    } else {
      for (int t = st; t < cs * CHK; ++t) {
        const f32x4_t v = *(const f32x4_t*)(hrow + (size_t)t * D_);
        a0 += v.x; a1 += v.y; a2 += v.z; a3 += v.w;
      }
#pragma unroll 4
      for (int c = cs; c < ce; ++c) {
        const f32x4_t v = *(const f32x4_t*)(crow + (size_t)c * D_);
        a0 += v.x; a1 += v.y; a2 += v.z; a3 += v.w;
      }
      for (int t = ce * CHK; t < en; ++t) {
        const f32x4_t v = *(const f32x4_t*)(hrow + (size_t)t * D_);
        a0 += v.x; a1 += v.y; a2 += v.z; a3 += v.w;
      }
    }
    const float cnt = (float)(en - st);
    const float inv = 1.f / (cnt + 1e-9f);
    a0 *= inv; a1 *= inv; a2 *= inv; a3 *= inv;
  }
  // PE: ang = s * 10000^(-e) = s * exp2(-e * log2(10000)); fast HW sincos
  const float L2_10K = 13.287712379549449f;
  const float e0 = (float)(4 * tid)     * (1.f / 1024.f);
  const float e1 = (float)(4 * tid + 2) * (1.f / 1024.f);
  const float ang0 = (float)s * exp2f(-e0 * L2_10K);
  const float ang1 = (float)s * exp2f(-e1 * L2_10K);
  float s0, c0, s1, c1;
  __sincosf(ang0, &s0, &c0);
  __sincosf(ang1, &s1, &c1);
  f32x4_t o;
  o.x = a0 + s0; o.y = a1 + c0; o.z = a2 + s1; o.w = a3 + c1;
  *(f32x4_t*)(pooled + ((size_t)(b * L_ + s)) * D_ + tid * 4) = o;
}

// ---------------------------------------------------------------------------
extern "C" void kernel_launch(void* const* d_in, const int* in_sizes, int n_in,
                              void* d_out, int out_size, void* d_ws, size_t ws_size,
                              hipStream_t stream)
{
  (void)in_sizes; (void)n_in; (void)out_size; (void)ws_size;
  const float* hidden = (const float*)d_in[0];
  const float* amask  = (const float*)d_in[1];
  const float* target = (const float*)d_in[2];
  const float* W1     = (const float*)d_in[3];
  const float* b1     = (const float*)d_in[4];
  const float* W2     = (const float*)d_in[5];
  const float* b2     = (const float*)d_in[6];

  float* out     = (float*)d_out;
  float* pooled  = out;                       // 16777216 floats (written LAST)
  float* out3    = out + 16777216;
  float* outmask = out + 16777219;

  // Abf (16MB) + Bbf (2MB) live inside the pooled output region as scratch;
  // k4b fully overwrites pooled afterwards.
  unsigned char* Abf = (unsigned char*)out;               // 16 MB
  unsigned char* Bbf = (unsigned char*)(out + 8388608);   // 2 MB at byte offset 32MB

  char* ws = (char*)d_ws;
  float* partial  = (float*)ws;                      ws += (size_t)16384 * NBLK * 4;  // 512 KB
  int*   seg      = (int*)ws;                        ws += (size_t)B_ * 2050 * 4;
  float* hdr      = (float*)ws;                      ws += (size_t)B_ * 4 * 4;
  float* logits   = (float*)ws;                      ws += (size_t)B_ * L_ * 4;       // 64 KB
  int*   flaglist = (int*)ws;                        ws += (size_t)MAXFLAG * 4;
  int*   flagcnt  = (int*)ws;                        ws += 256;
  float* fixpart  = (float*)ws;                      ws += (size_t)MAXFLAG * 8 * 4;   // 32 KB
  float* chunkSum = (float*)ws;                      // 2 MB

  k0a_packA<<<dim3(NK, 64), dim3(256), 0, stream>>>(hidden, Abf, chunkSum);
  k0b_packB<<<dim3(NK, 8), dim3(256), 0, stream>>>(W1, Bbf, flagcnt);
  k1_gemm<<<dim3(512), dim3(512), 65536, stream>>>(Abf, Bbf, b1, W2, partial);
  k2a_logits<<<dim3(64), dim3(256), 0, stream>>>(partial, b2, logits, flaglist, flagcnt);
  k2b_fixup<<<dim3(8, 64), dim3(256), 0, stream>>>(hidden, W1, b1, W2,
                                                   flaglist, flagcnt, fixpart);
  k2c_scan<<<dim3(8), dim3(256), 0, stream>>>(logits, amask, target, b2, fixpart,
                                              flaglist, flagcnt, outmask, seg, hdr);
  k4b_pool<<<dim3(16384), dim3(256), 0, stream>>>(hidden, chunkSum, seg, hdr, pooled, out3);
}

// Round 11
// 126.716 us; speedup vs baseline: 2.7985x; 2.7985x over previous
//
#include <hip/hip_runtime.h>
#include <math.h>

#define B_   8
#define L_   2048
#define D_   1024
#define H_   2048
#define NBLK 8             // H_/256 N-tiles in the GEMM
#define CHK  32            // tokens per chunk in pooling pre-pass
#define NCH  (L_ / CHK)    // 64 chunks per batch item
#define BK   64            // fp8: 64 k per tile (same bytes as bf16 BK=32)
#define NK   (D_ / BK)     // 16 K-steps
#define MARGIN  0.5f       // |logit| below this -> exact f32 recompute
#define MAXFLAG 1024
#define BSCALE  16.0f      // W1 pre-scale (exact pow2), undone in epilogue
#define BUNSCALE 0.0625f

typedef __bf16 bf16_t;
typedef float  f32x4_t  __attribute__((ext_vector_type(4)));
typedef int    i32x4_t  __attribute__((ext_vector_type(4)));
typedef long   i64x2_t  __attribute__((ext_vector_type(2)));

// Swizzled fp8 tile images: tile = 256 rows x BK(64) fp8 = 16KB, 64B/row.
// Logical chunk g (16B) of row r holds k = {g*8..g*8+7} CONCAT {32+g*8..32+g*8+7}
// (both ks-halves of lane-slot g), stored at physical chunk g ^ ((r>>1)&3).
// -> k1 frag read is ONE ds_read_b128/lane, 0 conflicts (round-9 verified).
#define TILE_BYTES 16384

__device__ inline int pk4_fp8(float a, float b, float c, float d) {
  int w = __builtin_amdgcn_cvt_pk_fp8_f32(a, b, 0, false);
  w = __builtin_amdgcn_cvt_pk_fp8_f32(c, d, w, true);
  return w;
}

// ---------------------------------------------------------------------------
// K0a (fused): hidden f32 -> Abf fp8 swizzled tiles AND 32-token chunk sums
// ---------------------------------------------------------------------------
__global__ __launch_bounds__(256) void k0a_packA(
    const float* __restrict__ A,      // [16384][1024]
    unsigned char* __restrict__ Abf,  // [64 mt][16 kt] tiles of 16KB
    float* __restrict__ chunkSum)     // [8][NCH][1024]
{
  __shared__ float scratch[256][65];
  const int kt = blockIdx.x;   // 0..15
  const int mt = blockIdx.y;   // 0..63
  const int r  = threadIdx.x;  // 0..255
  const float* src = A + (size_t)(mt * 256 + r) * D_ + kt * BK;
  float v[64];
#pragma unroll
  for (int q = 0; q < 16; ++q) {
    f32x4_t x = *(const f32x4_t*)(src + q * 4);
    v[q*4] = x.x; v[q*4+1] = x.y; v[q*4+2] = x.z; v[q*4+3] = x.w;
  }
  char* dst = (char*)Abf + ((size_t)(mt * 16 + kt)) * TILE_BYTES + r * 64;
#pragma unroll
  for (int g = 0; g < 4; ++g) {
    i32x4_t o;
    o[0] = pk4_fp8(v[g*8+0], v[g*8+1], v[g*8+2], v[g*8+3]);
    o[1] = pk4_fp8(v[g*8+4], v[g*8+5], v[g*8+6], v[g*8+7]);
    o[2] = pk4_fp8(v[32+g*8+0], v[32+g*8+1], v[32+g*8+2], v[32+g*8+3]);
    o[3] = pk4_fp8(v[32+g*8+4], v[32+g*8+5], v[32+g*8+6], v[32+g*8+7]);
    *(i32x4_t*)(dst + ((g ^ ((r >> 1) & 3)) << 4)) = o;
  }
  // chunk sums: tile spans 256 tokens = 8 chunks of 32, 64 dims
#pragma unroll
  for (int q = 0; q < 16; ++q)
    *(f32x4_t*)&scratch[r][q * 4] = *(const f32x4_t*)&v[q * 4];
  __syncthreads();
  const int ch = r >> 5, j2 = r & 31;
#pragma unroll
  for (int half = 0; half < 2; ++half) {
    const int j = j2 + half * 32;
    float s = 0.f;
#pragma unroll
    for (int q = 0; q < 32; ++q) s += scratch[ch * 32 + q][j];
    const int b  = mt >> 3;
    const int cg = (mt & 7) * 8 + ch;
    chunkSum[((size_t)(b * NCH + cg)) * D_ + kt * BK + j] = s;
  }
}

// ---------------------------------------------------------------------------
// K0b: W1 f32 -> Bbf fp8 swizzled tiles (x16 scale); also zeroes flagcnt
// ---------------------------------------------------------------------------
__global__ __launch_bounds__(256) void k0b_packB(
    const float* __restrict__ W1,     // [1024][2048]
    unsigned char* __restrict__ Bbf,  // [8 nt][16 kt] tiles of 16KB
    int* __restrict__ flagcnt)
{
  const int kt = blockIdx.x;   // 0..15
  const int nt = blockIdx.y;   // 0..7
  const int c  = threadIdx.x;  // 0..255
  if (kt == 0 && nt == 0 && c == 0) *flagcnt = 0;
  const float* src = W1 + (size_t)(kt * BK) * H_ + nt * 256 + c;
  float v[64];
#pragma unroll
  for (int j = 0; j < 64; ++j) v[j] = src[(size_t)j * H_] * BSCALE;
  char* dst = (char*)Bbf + ((size_t)(nt * 16 + kt)) * TILE_BYTES + c * 64;
#pragma unroll
  for (int g = 0; g < 4; ++g) {
    i32x4_t o;
    o[0] = pk4_fp8(v[g*8+0], v[g*8+1], v[g*8+2], v[g*8+3]);
    o[1] = pk4_fp8(v[g*8+4], v[g*8+5], v[g*8+6], v[g*8+7]);
    o[2] = pk4_fp8(v[32+g*8+0], v[32+g*8+1], v[32+g*8+2], v[32+g*8+3]);
    o[3] = pk4_fp8(v[32+g*8+4], v[32+g*8+5], v[32+g*8+6], v[32+g*8+7]);
    *(i32x4_t*)(dst + ((g ^ ((c >> 1) & 3)) << 4)) = o;
  }
}

// ---------------------------------------------------------------------------
// K1: fp8-e4m3 GEMM 256x256 tile, BK=64, 8 waves (2Mx4N, wave tile 128x64).
// Ring-2 LDS (2 x 32KB = 64KB; VGPR 112 + 64KB -> HW fits 2 blocks/CU),
// depth-1 prefetch, 2 barriers per K-step: barrier1 releases the overwrite
// target (WAR), counted vmcnt(4) + barrier2 makes stage(t) cross-wave
// visible while stage(t+1) stays in flight (never drains to 0 mid-loop).
// NOTE: launch_bounds min-waves stays 2 — forcing 4 caps VGPR and spills
// the accumulator to scratch (round-10: 904 MB scratch writes, 5x slower).
// Frag read: ONE ds_read_b128/lane (0 conflicts). Epilogue: relu(C/16+b1).W2.
// ---------------------------------------------------------------------------
__global__ __launch_bounds__(512, 2) void k1_gemm(
    const unsigned char* __restrict__ Abf,
    const unsigned char* __restrict__ Bbf,
    const float* __restrict__ b1,
    const float* __restrict__ W2,
    float* __restrict__ partial)    // [16384][NBLK]
{
  extern __shared__ __align__(16) unsigned char lds[];   // 65536 bytes

  const int tid  = threadIdx.x;           // 0..511
  // XCD-bijective swizzle (512 blocks % 8 == 0)
  const int wg   = (blockIdx.x & 7) * 64 + (blockIdx.x >> 3);
  const int mt   = wg >> 3;               // 0..63
  const int nt   = wg & 7;                // 0..7
  const int m0   = mt * 256;
  const int n0   = nt * 256;
  const int lane = tid & 63;
  const int wave = tid >> 6;              // 0..7
  const int wr = wave >> 2, wc = wave & 3;
  const int lr = lane & 15, lk = lane >> 4;

  const char* aT = (const char*)Abf + ((size_t)mt * NK) * TILE_BYTES;
  const char* bT = (const char*)Bbf + ((size_t)nt * NK) * TILE_BYTES;

  f32x4_t acc[8][4];
#pragma unroll
  for (int m = 0; m < 8; ++m)
#pragma unroll
    for (int n = 0; n < 4; ++n)
      acc[m][n] = (f32x4_t){0.f, 0.f, 0.f, 0.f};

  // stage K-step t into ring buffer buf: A tile 16KB then B tile 16KB
  auto stage = [&](int t, int buf) {
    const char* ga = aT + (size_t)t * TILE_BYTES;
    const char* gb = bT + (size_t)t * TILE_BYTES;
    unsigned char* lb = lds + buf * 32768;
#pragma unroll
    for (int j = 0; j < 4; ++j) {
      const int i = j * 512 + tid;        // 0..2047 16B-chunks
      const char* g = (j < 2) ? ga + i * 16 : gb + (i - 1024) * 16;
      __builtin_amdgcn_global_load_lds(
          (const __attribute__((address_space(1))) void*)g,
          (__attribute__((address_space(3))) void*)(lb + i * 16),
          16, 0, 0);
    }
  };

  stage(0, 0);
  for (int t = 0; t < NK; ++t) {
    __builtin_amdgcn_s_barrier();        // WAR: buf[(t+1)&1] free (compute(t-1) reads done)
    if (t + 1 < NK) {
      stage(t + 1, (t + 1) & 1);
      asm volatile("s_waitcnt vmcnt(4)" ::: "memory");   // stage(t) landed (per-wave)
    } else {
      asm volatile("s_waitcnt vmcnt(0)" ::: "memory");
    }
    __builtin_amdgcn_s_barrier();        // all waves' stage(t) shares visible
    asm volatile("" ::: "memory");       // no LDS reads hoist above barrier

    const char* sA = (const char*)(lds + (t & 1) * 32768);
    const char* sB = sA + 16384;
    // one b128 per frag: w.x = ks0 operand (k=lk*8+e), w.y = ks1 (k=32+lk*8+e)
    i64x2_t a[8], b[4];
#pragma unroll
    for (int m = 0; m < 8; ++m) {
      const int r = wr * 128 + m * 16 + lr;
      a[m] = *(const i64x2_t*)(sA + r * 64 + ((lk ^ ((r >> 1) & 3)) << 4));
    }
#pragma unroll
    for (int n = 0; n < 4; ++n) {
      const int c = wc * 64 + n * 16 + lr;
      b[n] = *(const i64x2_t*)(sB + c * 64 + ((lk ^ ((c >> 1) & 3)) << 4));
    }
    __builtin_amdgcn_s_setprio(1);
#pragma unroll
    for (int m = 0; m < 8; ++m)
#pragma unroll
      for (int n = 0; n < 4; ++n)
        acc[m][n] = __builtin_amdgcn_mfma_f32_16x16x32_fp8_fp8(
            a[m].x, b[n].x, acc[m][n], 0, 0, 0);
#pragma unroll
    for (int m = 0; m < 8; ++m)
#pragma unroll
      for (int n = 0; n < 4; ++n)
        acc[m][n] = __builtin_amdgcn_mfma_f32_16x16x32_fp8_fp8(
            a[m].y, b[n].y, acc[m][n], 0, 0, 0);
    __builtin_amdgcn_s_setprio(0);
  }

  // ---- epilogue: relu(C/16 + b1) * W2, reduce over cols, write partial ----
  float rs[8][4];
#pragma unroll
  for (int m = 0; m < 8; ++m)
#pragma unroll
    for (int rg = 0; rg < 4; ++rg) rs[m][rg] = 0.f;

#pragma unroll
  for (int n = 0; n < 4; ++n) {
    const int jg = n0 + wc * 64 + n * 16 + lr;   // C/D: col = lane&15
    const float w2v = W2[jg];
    const float b1v = b1[jg];
#pragma unroll
    for (int m = 0; m < 8; ++m)
#pragma unroll
      for (int rg = 0; rg < 4; ++rg) {
        float v = acc[m][n][rg] * BUNSCALE + b1v;
        rs[m][rg] += fmaxf(v, 0.f) * w2v;
      }
  }
#pragma unroll
  for (int m = 0; m < 8; ++m)
#pragma unroll
    for (int rg = 0; rg < 4; ++rg) {
      float v = rs[m][rg];
      v += __shfl_xor(v, 1);
      v += __shfl_xor(v, 2);
      v += __shfl_xor(v, 4);
      v += __shfl_xor(v, 8);
      rs[m][rg] = v;                      // col-sum of this wave's 64-col slab
    }
  __syncthreads();                        // all frag reads done; alias lds
  float (*part_lds)[4] = (float(*)[4])lds;   // [256][4]
  if (lr == 0) {
#pragma unroll
    for (int m = 0; m < 8; ++m)
#pragma unroll
      for (int rg = 0; rg < 4; ++rg)
        part_lds[wr * 128 + m * 16 + lk * 4 + rg][wc] = rs[m][rg];
  }
  __syncthreads();
  if (tid < 256) {
    const float sum = part_lds[tid][0] + part_lds[tid][1]
                    + part_lds[tid][2] + part_lds[tid][3];
    partial[(size_t)(m0 + tid) * NBLK + nt] = sum;
  }
}

// ---------------------------------------------------------------------------
// K2a: logits[i] = b2 + sum(partial[i][:]); flag near-threshold tokens
// ---------------------------------------------------------------------------
__global__ __launch_bounds__(256) void k2a_logits(
    const float* __restrict__ partial,
    const float* __restrict__ b2,
    float* __restrict__ logits,
    int* __restrict__ flaglist,
    int* __restrict__ flagcnt)
{
  const int i = blockIdx.x * 256 + threadIdx.x;   // 0..16383
  const float* pp = partial + (size_t)i * NBLK;
  float lg = b2[0];
#pragma unroll
  for (int j = 0; j < NBLK; ++j) lg += pp[j];
  logits[i] = lg;
  if (fabsf(lg) < MARGIN) {
    int s = atomicAdd(flagcnt, 1);
    if (s < MAXFLAG) flaglist[s] = i;
  }
}

// ---------------------------------------------------------------------------
// K2b: exact f32 recompute of flagged rows, split 8x by column group.
// grid (8 cg, 64 fslot); partials to fixpart[f][cg] (deterministic).
// ---------------------------------------------------------------------------
__global__ __launch_bounds__(256) void k2b_fixup(
    const float* __restrict__ hidden,
    const float* __restrict__ W1,
    const float* __restrict__ b1,
    const float* __restrict__ W2,
    const int* __restrict__ flaglist,
    const int* __restrict__ flagcnt,
    float* __restrict__ fixpart)         // [MAXFLAG][8]
{
  const int cnt = min(*flagcnt, MAXFLAG);
  const int cg = blockIdx.x;             // 0..7
  __shared__ float hrow[D_];
  __shared__ float red[256];
  const int tid = threadIdx.x;
  const int col = cg * 256 + tid;
  for (int f = blockIdx.y; f < cnt; f += 64) {
    const int i = flaglist[f];
    const float* h = hidden + (size_t)i * D_;
    __syncthreads();
    *(f32x4_t*)&hrow[tid * 4] = *(const f32x4_t*)&h[tid * 4];
    __syncthreads();
    float acc = 0.f;
#pragma unroll 8
    for (int k = 0; k < D_; ++k)
      acc = fmaf(hrow[k], W1[(size_t)k * H_ + col], acc);
    red[tid] = fmaxf(acc + b1[col], 0.f) * W2[col];
    __syncthreads();
    for (int st = 128; st > 0; st >>= 1) {
      if (tid < st) red[tid] += red[tid + st];
      __syncthreads();
    }
    if (tid == 0) fixpart[f * 8 + cg] = red[0];
  }
}

// ---------------------------------------------------------------------------
// K2c: per-batch scan. Prologue applies fixup combine for this batch's
// flagged tokens; then lengths, hb bits, parallel prefix scan, segment
// starts, shortened mask, binomial NLL.
// ---------------------------------------------------------------------------
__global__ __launch_bounds__(256) void k2c_scan(
    float* __restrict__ logits,          // [8][2048] (fixed in-place)
    const float* __restrict__ mask,      // [8][2048]
    const float* __restrict__ target,    // [8]
    const float* __restrict__ b2,
    const float* __restrict__ fixpart,   // [MAXFLAG][8]
    const int* __restrict__ flaglist,
    const int* __restrict__ flagcnt,
    float* __restrict__ outmask,         // [8][2048]
    int*   __restrict__ seg,             // [8][2050]
    float* __restrict__ hdr)             // [8][4]
{
  const int b = blockIdx.x, tid = threadIdx.x;
  __shared__ float redf[256];
  __shared__ int tsum[256];
  __shared__ unsigned char hbs[L_];

  // fix-combine for this batch's flagged tokens (exact f32 logits)
  const int cnt = min(*flagcnt, MAXFLAG);
  for (int f = tid; f < cnt; f += 256) {
    const int i = flaglist[f];
    if ((i >> 11) == b) {
      float s = b2[0];
#pragma unroll
      for (int cg = 0; cg < 8; ++cg) s += fixpart[f * 8 + cg];
      logits[i] = s;
    }
  }
  // length (tree reduce); the first barrier also orders the fixup writes
  float lm = 0.f;
#pragma unroll
  for (int e = 0; e < 8; ++e) lm += mask[b * L_ + tid * 8 + e];
  redf[tid] = lm;
  __syncthreads();
  for (int s = 128; s > 0; s >>= 1) {
    if (tid < s) redf[tid] += redf[tid + s];
    __syncthreads();
  }
  const int length = (int)(redf[0] + 0.5f);

  int hloc[8];
  int lsum = 0;
#pragma unroll
  for (int e = 0; e < 8; ++e) {
    const int t = tid * 8 + e;
    const float lg = logits[b * L_ + t];
    int hb = (lg > 0.f) && (t < length);
    if (length < L_ && t == length - 1) hb = 1;
    hloc[e] = hb;
    hbs[t] = (unsigned char)hb;
    lsum += hb;
  }
  // parallel inclusive scan (Hillis-Steele) over per-thread sums
  tsum[tid] = lsum;
  __syncthreads();
  for (int off = 1; off < 256; off <<= 1) {
    int v = tsum[tid];
    int add = (tid >= off) ? tsum[tid - off] : 0;
    __syncthreads();
    tsum[tid] = v + add;
    __syncthreads();
  }
  const int ktot = tsum[255];

  int pre = tsum[tid] - lsum;            // exclusive prefix
  for (int e = 0; e < 8; ++e) {
    const int t = tid * 8 + e;
    if (t < length) {
      const bool st = (t == 0) || hbs[t - 1];
      if (st) seg[b * 2050 + pre] = t;
    }
    pre += hloc[e];
  }

#pragma unroll
  for (int e = 0; e < 8; ++e) {
    const int t = tid * 8 + e;
    outmask[b * L_ + t] = (t < ktot) ? 1.f : 0.f;
  }

  __syncthreads();
  if (tid == 0) {
    const int maxseg = ktot - (length > 0 ? (int)hbs[length - 1] : 0);
    seg[b * 2050 + maxseg + 1] = length;
    const float n = (float)length, k = (float)ktot;
    float p = target[b] / fmaxf(n, 1.f);
    p = fminf(fmaxf(p, 1e-6f), 1.f - 1e-6f);
    const float lp = lgammaf(n + 1.f) - lgammaf(k + 1.f) - lgammaf(n - k + 1.f)
                   + k * logf(p) + (n - k) * log1pf(-p);
    hdr[b * 4 + 0] = n;
    hdr[b * 4 + 1] = k;
    hdr[b * 4 + 2] = (float)maxseg;
    hdr[b * 4 + 3] = -lp;
  }
}

// ---------------------------------------------------------------------------
// K4b: pooled[b][s][:] = mean(hidden[b][st:en][:]) + PE[s][:]
// segment mean = edge rows + full 32-token chunk sums. Block 0 also emits
// the three scalars.
// ---------------------------------------------------------------------------
__global__ __launch_bounds__(256) void k4b_pool(
    const float* __restrict__ hidden,
    const float* __restrict__ chunkSum,
    const int*   __restrict__ seg,
    const float* __restrict__ hdr,
    float* __restrict__ pooled,
    float* __restrict__ out3)
{
  const int bid = blockIdx.x;
  const int b = bid >> 11, s = bid & 2047;
  const int tid = threadIdx.x;
  if (bid == 0 && tid == 0) {
    float s_lp = 0.f, s_k = 0.f, s_n = 0.f;
    for (int i = 0; i < B_; ++i) {
      s_n  += hdr[i * 4 + 0];
      s_k  += hdr[i * 4 + 1];
      s_lp += hdr[i * 4 + 3];
    }
    out3[0] = 10.f * (s_lp * 0.125f);
    out3[1] = s_k;
    out3[2] = s_n;
  }
  const int maxseg = (int)hdr[b * 4 + 2];

  float a0 = 0.f, a1 = 0.f, a2 = 0.f, a3 = 0.f;
  if (s <= maxseg) {
    const int st = seg[b * 2050 + s];
    const int en = seg[b * 2050 + s + 1];
    const float* hrow = hidden + (size_t)(b * L_) * D_ + tid * 4;
    const float* crow = chunkSum + (size_t)(b * NCH) * D_ + tid * 4;
    const int cs = (st + CHK - 1) / CHK;
    const int ce = en / CHK;
    if (cs >= ce) {
      for (int t = st; t < en; ++t) {
        const f32x4_t v = *(const f32x4_t*)(hrow + (size_t)t * D_);
        a0 += v.x; a1 += v.y; a2 += v.z; a3 += v.w;
      }
    } else {
      for (int t = st; t < cs * CHK; ++t) {
        const f32x4_t v = *(const f32x4_t*)(hrow + (size_t)t * D_);
        a0 += v.x; a1 += v.y; a2 += v.z; a3 += v.w;
      }
#pragma unroll 4
      for (int c = cs; c < ce; ++c) {
        const f32x4_t v = *(const f32x4_t*)(crow + (size_t)c * D_);
        a0 += v.x; a1 += v.y; a2 += v.z; a3 += v.w;
      }
      for (int t = ce * CHK; t < en; ++t) {
        const f32x4_t v = *(const f32x4_t*)(hrow + (size_t)t * D_);
        a0 += v.x; a1 += v.y; a2 += v.z; a3 += v.w;
      }
    }
    const float cnt = (float)(en - st);
    const float inv = 1.f / (cnt + 1e-9f);
    a0 *= inv; a1 *= inv; a2 *= inv; a3 *= inv;
  }
  // PE: ang = s * 10000^(-e) = s * exp2(-e * log2(10000)); fast HW sincos
  const float L2_10K = 13.287712379549449f;
  const float e0 = (float)(4 * tid)     * (1.f / 1024.f);
  const float e1 = (float)(4 * tid + 2) * (1.f / 1024.f);
  const float ang0 = (float)s * exp2f(-e0 * L2_10K);
  const float ang1 = (float)s * exp2f(-e1 * L2_10K);
  float s0, c0, s1, c1;
  __sincosf(ang0, &s0, &c0);
  __sincosf(ang1, &s1, &c1);
  f32x4_t o;
  o.x = a0 + s0; o.y = a1 + c0; o.z = a2 + s1; o.w = a3 + c1;
  *(f32x4_t*)(pooled + ((size_t)(b * L_ + s)) * D_ + tid * 4) = o;
}

// ---------------------------------------------------------------------------
extern "C" void kernel_launch(void* const* d_in, const int* in_sizes, int n_in,
                              void* d_out, int out_size, void* d_ws, size_t ws_size,
                              hipStream_t stream)
{
  (void)in_sizes; (void)n_in; (void)out_size; (void)ws_size;
  const float* hidden = (const float*)d_in[0];
  const float* amask  = (const float*)d_in[1];
  const float* target = (const float*)d_in[2];
  const float* W1     = (const float*)d_in[3];
  const float* b1     = (const float*)d_in[4];
  const float* W2     = (const float*)d_in[5];
  const float* b2     = (const float*)d_in[6];

  float* out     = (float*)d_out;
  float* pooled  = out;                       // 16777216 floats (written LAST)
  float* out3    = out + 16777216;
  float* outmask = out + 16777219;

  // Abf (16MB) + Bbf (2MB) live inside the pooled output region as scratch;
  // k4b fully overwrites pooled afterwards.
  unsigned char* Abf = (unsigned char*)out;               // 16 MB
  unsigned char* Bbf = (unsigned char*)(out + 8388608);   // 2 MB at byte offset 32MB

  char* ws = (char*)d_ws;
  float* partial  = (float*)ws;                      ws += (size_t)16384 * NBLK * 4;  // 512 KB
  int*   seg      = (int*)ws;                        ws += (size_t)B_ * 2050 * 4;
  float* hdr      = (float*)ws;                      ws += (size_t)B_ * 4 * 4;
  float* logits   = (float*)ws;                      ws += (size_t)B_ * L_ * 4;       // 64 KB
  int*   flaglist = (int*)ws;                        ws += (size_t)MAXFLAG * 4;
  int*   flagcnt  = (int*)ws;                        ws += 256;
  float* fixpart  = (float*)ws;                      ws += (size_t)MAXFLAG * 8 * 4;   // 32 KB
  float* chunkSum = (float*)ws;                      // 2 MB

  k0a_packA<<<dim3(NK, 64), dim3(256), 0, stream>>>(hidden, Abf, chunkSum);
  k0b_packB<<<dim3(NK, 8), dim3(256), 0, stream>>>(W1, Bbf, flagcnt);
  k1_gemm<<<dim3(512), dim3(512), 65536, stream>>>(Abf, Bbf, b1, W2, partial);
  k2a_logits<<<dim3(64), dim3(256), 0, stream>>>(partial, b2, logits, flaglist, flagcnt);
  k2b_fixup<<<dim3(8, 64), dim3(256), 0, stream>>>(hidden, W1, b1, W2,
                                                   flaglist, flagcnt, fixpart);
  k2c_scan<<<dim3(8), dim3(256), 0, stream>>>(logits, amask, target, b2, fixpart,
                                              flaglist, flagcnt, outmask, seg, hdr);
  k4b_pool<<<dim3(16384), dim3(256), 0, stream>>>(hidden, chunkSum, seg, hdr, pooled, out3);
}

// Round 12
// 109.355 us; speedup vs baseline: 3.2427x; 1.1588x over previous
//
#include <hip/hip_runtime.h>
#include <math.h>

#define B_   8
#define L_   2048
#define D_   1024
#define H_   2048
#define NBLK 8             // H_/256 N-tiles in the GEMM
#define CHK  32            // tokens per chunk in pooling pre-pass
#define NCH  (L_ / CHK)    // 64 chunks per batch item
#define BK   64            // fp8: 64 k per tile
#define NK   (D_ / BK)     // 16 K-steps
#define MARGIN  0.5f       // |logit| below this -> exact f32 recompute
#define MAXFLAG 1024
#define BSCALE  16.0f      // W1 pre-scale (exact pow2), undone in epilogue
#define BUNSCALE 0.0625f

typedef __bf16 bf16_t;
typedef float  f32x4_t  __attribute__((ext_vector_type(4)));
typedef int    i32x4_t  __attribute__((ext_vector_type(4)));
typedef long   i64x2_t  __attribute__((ext_vector_type(2)));

// Swizzled fp8 tile images: tile = 256 rows x BK(64) fp8 = 16KB, 64B/row.
// Logical chunk g (16B) of row r holds k = {g*8..g*8+7} CONCAT {32+g*8..32+g*8+7}
// (both ks-halves of lane-slot g), stored at physical chunk g ^ ((r>>1)&3).
// -> k1 frag read is ONE ds_read_b128/lane, 0 conflicts (round-9 verified).
#define TILE_BYTES 16384

__device__ inline int pk4_fp8(float a, float b, float c, float d) {
  int w = __builtin_amdgcn_cvt_pk_fp8_f32(a, b, 0, false);
  w = __builtin_amdgcn_cvt_pk_fp8_f32(c, d, w, true);
  return w;
}

// ---------------------------------------------------------------------------
// K0 (merged): y<64: hidden -> Abf fp8 tiles + 32-token chunk sums
//              y>=64: W1 -> Bbf fp8 tiles (x16); zeroes flagcnt
// Scratch is [256][33] (34KB -> 4 blocks/CU); chunk sums done in 2 halves.
// ---------------------------------------------------------------------------
__global__ __launch_bounds__(256) void k0_pack(
    const float* __restrict__ A,      // [16384][1024]
    const float* __restrict__ W1,     // [1024][2048]
    unsigned char* __restrict__ Abf,  // [64 mt][16 kt] tiles of 16KB
    unsigned char* __restrict__ Bbf,  // [8 nt][16 kt] tiles of 16KB
    float* __restrict__ chunkSum,     // [8][NCH][1024]
    int* __restrict__ flagcnt)
{
  __shared__ float scratch[256][33];
  const int kt = blockIdx.x;   // 0..15
  const int yy = blockIdx.y;   // 0..71
  const int r  = threadIdx.x;  // 0..255

  if (yy >= 64) {              // ---- B path ----
    const int nt = yy - 64;
    if (kt == 0 && nt == 0 && r == 0) *flagcnt = 0;
    const float* src = W1 + (size_t)(kt * BK) * H_ + nt * 256 + r;
    float v[64];
#pragma unroll
    for (int j = 0; j < 64; ++j) v[j] = src[(size_t)j * H_] * BSCALE;
    char* dst = (char*)Bbf + ((size_t)(nt * 16 + kt)) * TILE_BYTES + r * 64;
#pragma unroll
    for (int g = 0; g < 4; ++g) {
      i32x4_t o;
      o[0] = pk4_fp8(v[g*8+0], v[g*8+1], v[g*8+2], v[g*8+3]);
      o[1] = pk4_fp8(v[g*8+4], v[g*8+5], v[g*8+6], v[g*8+7]);
      o[2] = pk4_fp8(v[32+g*8+0], v[32+g*8+1], v[32+g*8+2], v[32+g*8+3]);
      o[3] = pk4_fp8(v[32+g*8+4], v[32+g*8+5], v[32+g*8+6], v[32+g*8+7]);
      *(i32x4_t*)(dst + ((g ^ ((r >> 1) & 3)) << 4)) = o;
    }
    return;
  }

  // ---- A path ----
  const int mt = yy;
  const float* src = A + (size_t)(mt * 256 + r) * D_ + kt * BK;
  float v[64];
#pragma unroll
  for (int q = 0; q < 16; ++q) {
    f32x4_t x = *(const f32x4_t*)(src + q * 4);
    v[q*4] = x.x; v[q*4+1] = x.y; v[q*4+2] = x.z; v[q*4+3] = x.w;
  }
  char* dst = (char*)Abf + ((size_t)(mt * 16 + kt)) * TILE_BYTES + r * 64;
#pragma unroll
  for (int g = 0; g < 4; ++g) {
    i32x4_t o;
    o[0] = pk4_fp8(v[g*8+0], v[g*8+1], v[g*8+2], v[g*8+3]);
    o[1] = pk4_fp8(v[g*8+4], v[g*8+5], v[g*8+6], v[g*8+7]);
    o[2] = pk4_fp8(v[32+g*8+0], v[32+g*8+1], v[32+g*8+2], v[32+g*8+3]);
    o[3] = pk4_fp8(v[32+g*8+4], v[32+g*8+5], v[32+g*8+6], v[32+g*8+7]);
    *(i32x4_t*)(dst + ((g ^ ((r >> 1) & 3)) << 4)) = o;
  }
  // chunk sums in two 32-dim halves (scratch 34KB -> 4 blocks/CU)
  const int ch = r >> 5, j = r & 31;
  const int b  = mt >> 3;
  const int cg = (mt & 7) * 8 + ch;
#pragma unroll
  for (int half = 0; half < 2; ++half) {
    __syncthreads();
#pragma unroll
    for (int q = 0; q < 8; ++q)
      *(f32x4_t*)&scratch[r][q * 4] = *(const f32x4_t*)&v[half * 32 + q * 4];
    __syncthreads();
    float s = 0.f;
#pragma unroll
    for (int q = 0; q < 32; ++q) s += scratch[ch * 32 + q][j];
    chunkSum[((size_t)(b * NCH + cg)) * D_ + kt * BK + half * 32 + j] = s;
  }
}

// ---------------------------------------------------------------------------
// K1: fp8-e4m3 GEMM 256x256 tile, BK=64, 8 waves (2Mx4N, wave tile 128x64),
// mfma_f32_16x16x32_fp8_fp8. 4-way LDS ring (4 x 32KB), depth-2 prefetch via
// global_load_lds(16B), ONE raw s_barrier per K-step, counted vmcnt(8)
// (never 0 mid-loop). Frag read: ONE ds_read_b128/lane (0 conflicts).
// Epilogue: relu(C/16 + b1) . W2 row-reduce -> partial[m][nt].
// (Round-9 measured: 54.8 us, MfmaUtil 47%, FETCH 16.5MB, conflicts 0.)
// ---------------------------------------------------------------------------
__global__ __launch_bounds__(512, 2) void k1_gemm(
    const unsigned char* __restrict__ Abf,
    const unsigned char* __restrict__ Bbf,
    const float* __restrict__ b1,
    const float* __restrict__ W2,
    float* __restrict__ partial)    // [16384][NBLK]
{
  extern __shared__ __align__(16) unsigned char lds[];   // 131072 bytes

  const int tid  = threadIdx.x;           // 0..511
  // XCD-bijective swizzle (512 blocks % 8 == 0)
  const int wg   = (blockIdx.x & 7) * 64 + (blockIdx.x >> 3);
  const int mt   = wg >> 3;               // 0..63
  const int nt   = wg & 7;                // 0..7
  const int m0   = mt * 256;
  const int n0   = nt * 256;
  const int lane = tid & 63;
  const int wave = tid >> 6;              // 0..7
  const int wr = wave >> 2, wc = wave & 3;
  const int lr = lane & 15, lk = lane >> 4;

  const char* aT = (const char*)Abf + ((size_t)mt * NK) * TILE_BYTES;
  const char* bT = (const char*)Bbf + ((size_t)nt * NK) * TILE_BYTES;

  f32x4_t acc[8][4];
#pragma unroll
  for (int m = 0; m < 8; ++m)
#pragma unroll
    for (int n = 0; n < 4; ++n)
      acc[m][n] = (f32x4_t){0.f, 0.f, 0.f, 0.f};

  // stage K-step t into ring buffer buf: A tile 16KB then B tile 16KB
  auto stage = [&](int t, int buf) {
    const char* ga = aT + (size_t)t * TILE_BYTES;
    const char* gb = bT + (size_t)t * TILE_BYTES;
    unsigned char* lb = lds + buf * 32768;
#pragma unroll
    for (int j = 0; j < 4; ++j) {
      const int i = j * 512 + tid;        // 0..2047 16B-chunks
      const char* g = (j < 2) ? ga + i * 16 : gb + (i - 1024) * 16;
      __builtin_amdgcn_global_load_lds(
          (const __attribute__((address_space(1))) void*)g,
          (__attribute__((address_space(3))) void*)(lb + i * 16),
          16, 0, 0);
    }
  };

  stage(0, 0);
  stage(1, 1);
  for (int t = 0; t < NK; ++t) {
    if (t + 2 < NK) {
      stage(t + 2, (t + 2) & 3);
      asm volatile("s_waitcnt vmcnt(8)" ::: "memory");   // stage(t) landed
    } else if (t + 1 < NK) {
      asm volatile("s_waitcnt vmcnt(4)" ::: "memory");
    } else {
      asm volatile("s_waitcnt vmcnt(0)" ::: "memory");
    }
    __builtin_amdgcn_s_barrier();        // all waves' stage(t) shares visible
    asm volatile("" ::: "memory");       // no LDS reads hoist above barrier

    const char* sA = (const char*)(lds + (t & 3) * 32768);
    const char* sB = sA + 16384;
    // one b128 per frag: w.x = ks0 operand (k=lk*8+e), w.y = ks1 (k=32+lk*8+e)
    i64x2_t a[8], b[4];
#pragma unroll
    for (int m = 0; m < 8; ++m) {
      const int r = wr * 128 + m * 16 + lr;
      a[m] = *(const i64x2_t*)(sA + r * 64 + ((lk ^ ((r >> 1) & 3)) << 4));
    }
#pragma unroll
    for (int n = 0; n < 4; ++n) {
      const int c = wc * 64 + n * 16 + lr;
      b[n] = *(const i64x2_t*)(sB + c * 64 + ((lk ^ ((c >> 1) & 3)) << 4));
    }
    __builtin_amdgcn_s_setprio(1);
#pragma unroll
    for (int m = 0; m < 8; ++m)
#pragma unroll
      for (int n = 0; n < 4; ++n)
        acc[m][n] = __builtin_amdgcn_mfma_f32_16x16x32_fp8_fp8(
            a[m].x, b[n].x, acc[m][n], 0, 0, 0);
#pragma unroll
    for (int m = 0; m < 8; ++m)
#pragma unroll
      for (int n = 0; n < 4; ++n)
        acc[m][n] = __builtin_amdgcn_mfma_f32_16x16x32_fp8_fp8(
            a[m].y, b[n].y, acc[m][n], 0, 0, 0);
    __builtin_amdgcn_s_setprio(0);
  }

  // ---- epilogue: relu(C/16 + b1) * W2, reduce over cols, write partial ----
  float rs[8][4];
#pragma unroll
  for (int m = 0; m < 8; ++m)
#pragma unroll
    for (int rg = 0; rg < 4; ++rg) rs[m][rg] = 0.f;

#pragma unroll
  for (int n = 0; n < 4; ++n) {
    const int jg = n0 + wc * 64 + n * 16 + lr;   // C/D: col = lane&15
    const float w2v = W2[jg];
    const float b1v = b1[jg];
#pragma unroll
    for (int m = 0; m < 8; ++m)
#pragma unroll
      for (int rg = 0; rg < 4; ++rg) {
        float v = acc[m][n][rg] * BUNSCALE + b1v;
        rs[m][rg] += fmaxf(v, 0.f) * w2v;
      }
  }
#pragma unroll
  for (int m = 0; m < 8; ++m)
#pragma unroll
    for (int rg = 0; rg < 4; ++rg) {
      float v = rs[m][rg];
      v += __shfl_xor(v, 1);
      v += __shfl_xor(v, 2);
      v += __shfl_xor(v, 4);
      v += __shfl_xor(v, 8);
      rs[m][rg] = v;                      // col-sum of this wave's 64-col slab
    }
  __syncthreads();                        // all frag reads done; alias lds
  float (*part_lds)[4] = (float(*)[4])lds;   // [256][4]
  if (lr == 0) {
#pragma unroll
    for (int m = 0; m < 8; ++m)
#pragma unroll
      for (int rg = 0; rg < 4; ++rg)
        part_lds[wr * 128 + m * 16 + lk * 4 + rg][wc] = rs[m][rg];
  }
  __syncthreads();
  if (tid < 256) {
    const float sum = part_lds[tid][0] + part_lds[tid][1]
                    + part_lds[tid][2] + part_lds[tid][3];
    partial[(size_t)(m0 + tid) * NBLK + nt] = sum;
  }
}

// ---------------------------------------------------------------------------
// K2a: logits[i] = b2 + sum(partial[i][:]); flag near-threshold tokens
// ---------------------------------------------------------------------------
__global__ __launch_bounds__(256) void k2a_logits(
    const float* __restrict__ partial,
    const float* __restrict__ b2,
    float* __restrict__ logits,
    int* __restrict__ flaglist,
    int* __restrict__ flagcnt)
{
  const int i = blockIdx.x * 256 + threadIdx.x;   // 0..16383
  const float* pp = partial + (size_t)i * NBLK;
  float lg = b2[0];
#pragma unroll
  for (int j = 0; j < NBLK; ++j) lg += pp[j];
  logits[i] = lg;
  if (fabsf(lg) < MARGIN) {
    int s = atomicAdd(flagcnt, 1);
    if (s < MAXFLAG) flaglist[s] = i;
  }
}

// ---------------------------------------------------------------------------
// K2b: exact f32 recompute of flagged rows, split 8x by column group.
// grid (8 cg, 64 fslot); partials to fixpart[f][cg] (deterministic).
// ---------------------------------------------------------------------------
__global__ __launch_bounds__(256) void k2b_fixup(
    const float* __restrict__ hidden,
    const float* __restrict__ W1,
    const float* __restrict__ b1,
    const float* __restrict__ W2,
    const int* __restrict__ flaglist,
    const int* __restrict__ flagcnt,
    float* __restrict__ fixpart)         // [MAXFLAG][8]
{
  const int cnt = min(*flagcnt, MAXFLAG);
  const int cg = blockIdx.x;             // 0..7
  __shared__ float hrow[D_];
  __shared__ float red[256];
  const int tid = threadIdx.x;
  const int col = cg * 256 + tid;
  for (int f = blockIdx.y; f < cnt; f += 64) {
    const int i = flaglist[f];
    const float* h = hidden + (size_t)i * D_;
    __syncthreads();
    *(f32x4_t*)&hrow[tid * 4] = *(const f32x4_t*)&h[tid * 4];
    __syncthreads();
    float acc = 0.f;
#pragma unroll 8
    for (int k = 0; k < D_; ++k)
      acc = fmaf(hrow[k], W1[(size_t)k * H_ + col], acc);
    red[tid] = fmaxf(acc + b1[col], 0.f) * W2[col];
    __syncthreads();
    for (int st = 128; st > 0; st >>= 1) {
      if (tid < st) red[tid] += red[tid + st];
      __syncthreads();
    }
    if (tid == 0) fixpart[f * 8 + cg] = red[0];
  }
}

// ---------------------------------------------------------------------------
// K2c: per-batch scan. Prologue applies fixup combine for this batch's
// flagged tokens; then lengths, hb bits, parallel prefix scan, segment
// starts, shortened mask, binomial NLL.
// ---------------------------------------------------------------------------
__global__ __launch_bounds__(256) void k2c_scan(
    float* __restrict__ logits,          // [8][2048] (fixed in-place)
    const float* __restrict__ mask,      // [8][2048]
    const float* __restrict__ target,    // [8]
    const float* __restrict__ b2,
    const float* __restrict__ fixpart,   // [MAXFLAG][8]
    const int* __restrict__ flaglist,
    const int* __restrict__ flagcnt,
    float* __restrict__ outmask,         // [8][2048]
    int*   __restrict__ seg,             // [8][2050]
    float* __restrict__ hdr)             // [8][4]
{
  const int b = blockIdx.x, tid = threadIdx.x;
  __shared__ float redf[256];
  __shared__ int tsum[256];
  __shared__ unsigned char hbs[L_];

  // fix-combine for this batch's flagged tokens (exact f32 logits)
  const int cnt = min(*flagcnt, MAXFLAG);
  for (int f = tid; f < cnt; f += 256) {
    const int i = flaglist[f];
    if ((i >> 11) == b) {
      float s = b2[0];
#pragma unroll
      for (int cg = 0; cg < 8; ++cg) s += fixpart[f * 8 + cg];
      logits[i] = s;
    }
  }
  // length (tree reduce); the first barrier also orders the fixup writes
  float lm = 0.f;
#pragma unroll
  for (int e = 0; e < 8; ++e) lm += mask[b * L_ + tid * 8 + e];
  redf[tid] = lm;
  __syncthreads();
  for (int s = 128; s > 0; s >>= 1) {
    if (tid < s) redf[tid] += redf[tid + s];
    __syncthreads();
  }
  const int length = (int)(redf[0] + 0.5f);

  int hloc[8];
  int lsum = 0;
#pragma unroll
  for (int e = 0; e < 8; ++e) {
    const int t = tid * 8 + e;
    const float lg = logits[b * L_ + t];
    int hb = (lg > 0.f) && (t < length);
    if (length < L_ && t == length - 1) hb = 1;
    hloc[e] = hb;
    hbs[t] = (unsigned char)hb;
    lsum += hb;
  }
  // parallel inclusive scan (Hillis-Steele) over per-thread sums
  tsum[tid] = lsum;
  __syncthreads();
  for (int off = 1; off < 256; off <<= 1) {
    int v = tsum[tid];
    int add = (tid >= off) ? tsum[tid - off] : 0;
    __syncthreads();
    tsum[tid] = v + add;
    __syncthreads();
  }
  const int ktot = tsum[255];

  int pre = tsum[tid] - lsum;            // exclusive prefix
  for (int e = 0; e < 8; ++e) {
    const int t = tid * 8 + e;
    if (t < length) {
      const bool st = (t == 0) || hbs[t - 1];
      if (st) seg[b * 2050 + pre] = t;
    }
    pre += hloc[e];
  }

#pragma unroll
  for (int e = 0; e < 8; ++e) {
    const int t = tid * 8 + e;
    outmask[b * L_ + t] = (t < ktot) ? 1.f : 0.f;
  }

  __syncthreads();
  if (tid == 0) {
    const int maxseg = ktot - (length > 0 ? (int)hbs[length - 1] : 0);
    seg[b * 2050 + maxseg + 1] = length;
    const float n = (float)length, k = (float)ktot;
    float p = target[b] / fmaxf(n, 1.f);
    p = fminf(fmaxf(p, 1e-6f), 1.f - 1e-6f);
    const float lp = lgammaf(n + 1.f) - lgammaf(k + 1.f) - lgammaf(n - k + 1.f)
                   + k * logf(p) + (n - k) * log1pf(-p);
    hdr[b * 4 + 0] = n;
    hdr[b * 4 + 1] = k;
    hdr[b * 4 + 2] = (float)maxseg;
    hdr[b * 4 + 3] = -lp;
  }
}

// ---------------------------------------------------------------------------
// K4b: pooled[b][s][:] = mean(hidden[b][st:en][:]) + PE[s][:]
// segment mean = edge rows + full 32-token chunk sums. Block 0 also emits
// the three scalars.
// ---------------------------------------------------------------------------
__global__ __launch_bounds__(256) void k4b_pool(
    const float* __restrict__ hidden,
    const float* __restrict__ chunkSum,
    const int*   __restrict__ seg,
    const float* __restrict__ hdr,
    float* __restrict__ pooled,
    float* __restrict__ out3)
{
  const int bid = blockIdx.x;
  const int b = bid >> 11, s = bid & 2047;
  const int tid = threadIdx.x;
  if (bid == 0 && tid == 0) {
    float s_lp = 0.f, s_k = 0.f, s_n = 0.f;
    for (int i = 0; i < B_; ++i) {
      s_n  += hdr[i * 4 + 0];
      s_k  += hdr[i * 4 + 1];
      s_lp += hdr[i * 4 + 3];
    }
    out3[0] = 10.f * (s_lp * 0.125f);
    out3[1] = s_k;
    out3[2] = s_n;
  }
  const int maxseg = (int)hdr[b * 4 + 2];

  float a0 = 0.f, a1 = 0.f, a2 = 0.f, a3 = 0.f;
  if (s <= maxseg) {
    const int st = seg[b * 2050 + s];
    const int en = seg[b * 2050 + s + 1];
    const float* hrow = hidden + (size_t)(b * L_) * D_ + tid * 4;
    const float* crow = chunkSum + (size_t)(b * NCH) * D_ + tid * 4;
    const int cs = (st + CHK - 1) / CHK;
    const int ce = en / CHK;
    if (cs >= ce) {
      for (int t = st; t < en; ++t) {
        const f32x4_t v = *(const f32x4_t*)(hrow + (size_t)t * D_);
        a0 += v.x; a1 += v.y; a2 += v.z; a3 += v.w;
      }
    } else {
      for (int t = st; t < cs * CHK; ++t) {
        const f32x4_t v = *(const f32x4_t*)(hrow + (size_t)t * D_);
        a0 += v.x; a1 += v.y; a2 += v.z; a3 += v.w;
      }
#pragma unroll 4
      for (int c = cs; c < ce; ++c) {
        const f32x4_t v = *(const f32x4_t*)(crow + (size_t)c * D_);
        a0 += v.x; a1 += v.y; a2 += v.z; a3 += v.w;
      }
      for (int t = ce * CHK; t < en; ++t) {
        const f32x4_t v = *(const f32x4_t*)(hrow + (size_t)t * D_);
        a0 += v.x; a1 += v.y; a2 += v.z; a3 += v.w;
      }
    }
    const float cnt = (float)(en - st);
    const float inv = 1.f / (cnt + 1e-9f);
    a0 *= inv; a1 *= inv; a2 *= inv; a3 *= inv;
  }
  // PE: ang = s * 10000^(-e) = s * exp2(-e * log2(10000)); fast HW sincos
  const float L2_10K = 13.287712379549449f;
  const float e0 = (float)(4 * tid)     * (1.f / 1024.f);
  const float e1 = (float)(4 * tid + 2) * (1.f / 1024.f);
  const float ang0 = (float)s * exp2f(-e0 * L2_10K);
  const float ang1 = (float)s * exp2f(-e1 * L2_10K);
  float s0, c0, s1, c1;
  __sincosf(ang0, &s0, &c0);
  __sincosf(ang1, &s1, &c1);
  f32x4_t o;
  o.x = a0 + s0; o.y = a1 + c0; o.z = a2 + s1; o.w = a3 + c1;
  *(f32x4_t*)(pooled + ((size_t)(b * L_ + s)) * D_ + tid * 4) = o;
}

// ---------------------------------------------------------------------------
extern "C" void kernel_launch(void* const* d_in, const int* in_sizes, int n_in,
                              void* d_out, int out_size, void* d_ws, size_t ws_size,
                              hipStream_t stream)
{
  (void)in_sizes; (void)n_in; (void)out_size; (void)ws_size;
  const float* hidden = (const float*)d_in[0];
  const float* amask  = (const float*)d_in[1];
  const float* target = (const float*)d_in[2];
  const float* W1     = (const float*)d_in[3];
  const float* b1     = (const float*)d_in[4];
  const float* W2     = (const float*)d_in[5];
  const float* b2     = (const float*)d_in[6];

  float* out     = (float*)d_out;
  float* pooled  = out;                       // 16777216 floats (written LAST)
  float* out3    = out + 16777216;
  float* outmask = out + 16777219;

  // Abf (16MB) + Bbf (2MB) live inside the pooled output region as scratch;
  // k4b fully overwrites pooled afterwards.
  unsigned char* Abf = (unsigned char*)out;               // 16 MB
  unsigned char* Bbf = (unsigned char*)(out + 8388608);   // 2 MB at byte offset 32MB

  char* ws = (char*)d_ws;
  float* partial  = (float*)ws;                      ws += (size_t)16384 * NBLK * 4;  // 512 KB
  int*   seg      = (int*)ws;                        ws += (size_t)B_ * 2050 * 4;
  float* hdr      = (float*)ws;                      ws += (size_t)B_ * 4 * 4;
  float* logits   = (float*)ws;                      ws += (size_t)B_ * L_ * 4;       // 64 KB
  int*   flaglist = (int*)ws;                        ws += (size_t)MAXFLAG * 4;
  int*   flagcnt  = (int*)ws;                        ws += 256;
  float* fixpart  = (float*)ws;                      ws += (size_t)MAXFLAG * 8 * 4;   // 32 KB
  float* chunkSum = (float*)ws;                      // 2 MB

  k0_pack<<<dim3(NK, 72), dim3(256), 0, stream>>>(hidden, W1, Abf, Bbf,
                                                  chunkSum, flagcnt);
  k1_gemm<<<dim3(512), dim3(512), 131072, stream>>>(Abf, Bbf, b1, W2, partial);
  k2a_logits<<<dim3(64), dim3(256), 0, stream>>>(partial, b2, logits, flaglist, flagcnt);
  k2b_fixup<<<dim3(8, 64), dim3(256), 0, stream>>>(hidden, W1, b1, W2,
                                                   flaglist, flagcnt, fixpart);
  k2c_scan<<<dim3(8), dim3(256), 0, stream>>>(logits, amask, target, b2, fixpart,
                                              flaglist, flagcnt, outmask, seg, hdr);
  k4b_pool<<<dim3(16384), dim3(256), 0, stream>>>(hidden, chunkSum, seg, hdr, pooled, out3);
}

// Round 13
// 107.421 us; speedup vs baseline: 3.3011x; 1.0180x over previous
//
#include <hip/hip_runtime.h>
#include <math.h>

#define B_   8
#define L_   2048
#define D_   1024
#define H_   2048
#define NBLK 8             // H_/256 N-tiles in the GEMM
#define CHK  32            // tokens per chunk in pooling pre-pass
#define NCH  (L_ / CHK)    // 64 chunks per batch item
#define BK   64            // fp8: 64 k per tile
#define NK   (D_ / BK)     // 16 K-steps
#define MARGIN  0.5f       // |logit| below this -> exact f32 recompute
#define MAXFLAG 1024
#define BSCALE  16.0f      // W1 pre-scale (exact pow2), undone in epilogue
#define BUNSCALE 0.0625f

typedef __bf16 bf16_t;
typedef float  f32x4_t  __attribute__((ext_vector_type(4)));
typedef int    i32x4_t  __attribute__((ext_vector_type(4)));
typedef long   i64x2_t  __attribute__((ext_vector_type(2)));

// Swizzled fp8 tile images: tile = 256 rows x BK(64) fp8 = 16KB, 64B/row.
// Logical chunk g (16B) of row r holds k = {g*8..g*8+7} CONCAT {32+g*8..32+g*8+7}
// (both ks-halves of lane-slot g), stored at physical chunk g ^ ((r>>1)&3).
// -> k1 frag read is ONE ds_read_b128/lane, 0 conflicts (round-9 verified).
#define TILE_BYTES 16384

__device__ inline int pk4_fp8(float a, float b, float c, float d) {
  int w = __builtin_amdgcn_cvt_pk_fp8_f32(a, b, 0, false);
  w = __builtin_amdgcn_cvt_pk_fp8_f32(c, d, w, true);
  return w;
}

// ---------------------------------------------------------------------------
// K0 (merged): y<64: hidden -> Abf fp8 tiles + 32-token chunk sums
//              y>=64: W1 -> Bbf fp8 tiles (x16); zeroes flagcnt
// Scratch is [256][33] (34KB -> 4 blocks/CU); chunk sums done in 2 halves.
// ---------------------------------------------------------------------------
__global__ __launch_bounds__(256) void k0_pack(
    const float* __restrict__ A,      // [16384][1024]
    const float* __restrict__ W1,     // [1024][2048]
    unsigned char* __restrict__ Abf,  // [64 mt][16 kt] tiles of 16KB
    unsigned char* __restrict__ Bbf,  // [8 nt][16 kt] tiles of 16KB
    float* __restrict__ chunkSum,     // [8][NCH][1024]
    int* __restrict__ flagcnt)
{
  __shared__ float scratch[256][33];
  const int kt = blockIdx.x;   // 0..15
  const int yy = blockIdx.y;   // 0..71
  const int r  = threadIdx.x;  // 0..255

  if (yy >= 64) {              // ---- B path ----
    const int nt = yy - 64;
    if (kt == 0 && nt == 0 && r == 0) *flagcnt = 0;
    const float* src = W1 + (size_t)(kt * BK) * H_ + nt * 256 + r;
    float v[64];
#pragma unroll
    for (int j = 0; j < 64; ++j) v[j] = src[(size_t)j * H_] * BSCALE;
    char* dst = (char*)Bbf + ((size_t)(nt * 16 + kt)) * TILE_BYTES + r * 64;
#pragma unroll
    for (int g = 0; g < 4; ++g) {
      i32x4_t o;
      o[0] = pk4_fp8(v[g*8+0], v[g*8+1], v[g*8+2], v[g*8+3]);
      o[1] = pk4_fp8(v[g*8+4], v[g*8+5], v[g*8+6], v[g*8+7]);
      o[2] = pk4_fp8(v[32+g*8+0], v[32+g*8+1], v[32+g*8+2], v[32+g*8+3]);
      o[3] = pk4_fp8(v[32+g*8+4], v[32+g*8+5], v[32+g*8+6], v[32+g*8+7]);
      *(i32x4_t*)(dst + ((g ^ ((r >> 1) & 3)) << 4)) = o;
    }
    return;
  }

  // ---- A path ----
  const int mt = yy;
  const float* src = A + (size_t)(mt * 256 + r) * D_ + kt * BK;
  float v[64];
#pragma unroll
  for (int q = 0; q < 16; ++q) {
    f32x4_t x = *(const f32x4_t*)(src + q * 4);
    v[q*4] = x.x; v[q*4+1] = x.y; v[q*4+2] = x.z; v[q*4+3] = x.w;
  }
  char* dst = (char*)Abf + ((size_t)(mt * 16 + kt)) * TILE_BYTES + r * 64;
#pragma unroll
  for (int g = 0; g < 4; ++g) {
    i32x4_t o;
    o[0] = pk4_fp8(v[g*8+0], v[g*8+1], v[g*8+2], v[g*8+3]);
    o[1] = pk4_fp8(v[g*8+4], v[g*8+5], v[g*8+6], v[g*8+7]);
    o[2] = pk4_fp8(v[32+g*8+0], v[32+g*8+1], v[32+g*8+2], v[32+g*8+3]);
    o[3] = pk4_fp8(v[32+g*8+4], v[32+g*8+5], v[32+g*8+6], v[32+g*8+7]);
    *(i32x4_t*)(dst + ((g ^ ((r >> 1) & 3)) << 4)) = o;
  }
  // chunk sums in two 32-dim halves (scratch 34KB -> 4 blocks/CU)
  const int ch = r >> 5, j = r & 31;
  const int b  = mt >> 3;
  const int cg = (mt & 7) * 8 + ch;
#pragma unroll
  for (int half = 0; half < 2; ++half) {
    __syncthreads();
#pragma unroll
    for (int q = 0; q < 8; ++q)
      *(f32x4_t*)&scratch[r][q * 4] = *(const f32x4_t*)&v[half * 32 + q * 4];
    __syncthreads();
    float s = 0.f;
#pragma unroll
    for (int q = 0; q < 32; ++q) s += scratch[ch * 32 + q][j];
    chunkSum[((size_t)(b * NCH + cg)) * D_ + kt * BK + half * 32 + j] = s;
  }
}

// ---------------------------------------------------------------------------
// K1: fp8-e4m3 GEMM 256x256 tile, BK=64, 8 waves (2Mx4N, wave tile 128x64),
// mfma_f32_16x16x32_fp8_fp8. 4-way LDS ring (4 x 32KB), depth-2 prefetch via
// global_load_lds(16B), ONE raw s_barrier per K-step, counted vmcnt(8)
// (never 0 mid-loop). Frag read: ONE ds_read_b128/lane (0 conflicts).
// setprio REMOVED this round (T5/m190: ~0 to negative on lockstep GEMM).
// Epilogue: relu(C/16 + b1) . W2 row-reduce -> partial[m][nt].
// ---------------------------------------------------------------------------
__global__ __launch_bounds__(512, 2) void k1_gemm(
    const unsigned char* __restrict__ Abf,
    const unsigned char* __restrict__ Bbf,
    const float* __restrict__ b1,
    const float* __restrict__ W2,
    float* __restrict__ partial)    // [16384][NBLK]
{
  extern __shared__ __align__(16) unsigned char lds[];   // 131072 bytes

  const int tid  = threadIdx.x;           // 0..511
  // XCD-bijective swizzle (512 blocks % 8 == 0)
  const int wg   = (blockIdx.x & 7) * 64 + (blockIdx.x >> 3);
  const int mt   = wg >> 3;               // 0..63
  const int nt   = wg & 7;                // 0..7
  const int m0   = mt * 256;
  const int n0   = nt * 256;
  const int lane = tid & 63;
  const int wave = tid >> 6;              // 0..7
  const int wr = wave >> 2, wc = wave & 3;
  const int lr = lane & 15, lk = lane >> 4;

  const char* aT = (const char*)Abf + ((size_t)mt * NK) * TILE_BYTES;
  const char* bT = (const char*)Bbf + ((size_t)nt * NK) * TILE_BYTES;

  f32x4_t acc[8][4];
#pragma unroll
  for (int m = 0; m < 8; ++m)
#pragma unroll
    for (int n = 0; n < 4; ++n)
      acc[m][n] = (f32x4_t){0.f, 0.f, 0.f, 0.f};

  // stage K-step t into ring buffer buf: A tile 16KB then B tile 16KB
  auto stage = [&](int t, int buf) {
    const char* ga = aT + (size_t)t * TILE_BYTES;
    const char* gb = bT + (size_t)t * TILE_BYTES;
    unsigned char* lb = lds + buf * 32768;
#pragma unroll
    for (int j = 0; j < 4; ++j) {
      const int i = j * 512 + tid;        // 0..2047 16B-chunks
      const char* g = (j < 2) ? ga + i * 16 : gb + (i - 1024) * 16;
      __builtin_amdgcn_global_load_lds(
          (const __attribute__((address_space(1))) void*)g,
          (__attribute__((address_space(3))) void*)(lb + i * 16),
          16, 0, 0);
    }
  };

  stage(0, 0);
  stage(1, 1);
  for (int t = 0; t < NK; ++t) {
    if (t + 2 < NK) {
      stage(t + 2, (t + 2) & 3);
      asm volatile("s_waitcnt vmcnt(8)" ::: "memory");   // stage(t) landed
    } else if (t + 1 < NK) {
      asm volatile("s_waitcnt vmcnt(4)" ::: "memory");
    } else {
      asm volatile("s_waitcnt vmcnt(0)" ::: "memory");
    }
    __builtin_amdgcn_s_barrier();        // all waves' stage(t) shares visible
    asm volatile("" ::: "memory");       // no LDS reads hoist above barrier

    const char* sA = (const char*)(lds + (t & 3) * 32768);
    const char* sB = sA + 16384;
    // one b128 per frag: w.x = ks0 operand (k=lk*8+e), w.y = ks1 (k=32+lk*8+e)
    i64x2_t a[8], b[4];
#pragma unroll
    for (int m = 0; m < 8; ++m) {
      const int r = wr * 128 + m * 16 + lr;
      a[m] = *(const i64x2_t*)(sA + r * 64 + ((lk ^ ((r >> 1) & 3)) << 4));
    }
#pragma unroll
    for (int n = 0; n < 4; ++n) {
      const int c = wc * 64 + n * 16 + lr;
      b[n] = *(const i64x2_t*)(sB + c * 64 + ((lk ^ ((c >> 1) & 3)) << 4));
    }
#pragma unroll
    for (int m = 0; m < 8; ++m)
#pragma unroll
      for (int n = 0; n < 4; ++n)
        acc[m][n] = __builtin_amdgcn_mfma_f32_16x16x32_fp8_fp8(
            a[m].x, b[n].x, acc[m][n], 0, 0, 0);
#pragma unroll
    for (int m = 0; m < 8; ++m)
#pragma unroll
      for (int n = 0; n < 4; ++n)
        acc[m][n] = __builtin_amdgcn_mfma_f32_16x16x32_fp8_fp8(
            a[m].y, b[n].y, acc[m][n], 0, 0, 0);
  }

  // ---- epilogue: relu(C/16 + b1) * W2, reduce over cols, write partial ----
  float rs[8][4];
#pragma unroll
  for (int m = 0; m < 8; ++m)
#pragma unroll
    for (int rg = 0; rg < 4; ++rg) rs[m][rg] = 0.f;

#pragma unroll
  for (int n = 0; n < 4; ++n) {
    const int jg = n0 + wc * 64 + n * 16 + lr;   // C/D: col = lane&15
    const float w2v = W2[jg];
    const float b1v = b1[jg];
#pragma unroll
    for (int m = 0; m < 8; ++m)
#pragma unroll
      for (int rg = 0; rg < 4; ++rg) {
        float v = acc[m][n][rg] * BUNSCALE + b1v;
        rs[m][rg] += fmaxf(v, 0.f) * w2v;
      }
  }
#pragma unroll
  for (int m = 0; m < 8; ++m)
#pragma unroll
    for (int rg = 0; rg < 4; ++rg) {
      float v = rs[m][rg];
      v += __shfl_xor(v, 1);
      v += __shfl_xor(v, 2);
      v += __shfl_xor(v, 4);
      v += __shfl_xor(v, 8);
      rs[m][rg] = v;                      // col-sum of this wave's 64-col slab
    }
  __syncthreads();                        // all frag reads done; alias lds
  float (*part_lds)[4] = (float(*)[4])lds;   // [256][4]
  if (lr == 0) {
#pragma unroll
    for (int m = 0; m < 8; ++m)
#pragma unroll
      for (int rg = 0; rg < 4; ++rg)
        part_lds[wr * 128 + m * 16 + lk * 4 + rg][wc] = rs[m][rg];
  }
  __syncthreads();
  if (tid < 256) {
    const float sum = part_lds[tid][0] + part_lds[tid][1]
                    + part_lds[tid][2] + part_lds[tid][3];
    partial[(size_t)(m0 + tid) * NBLK + nt] = sum;
  }
}

// ---------------------------------------------------------------------------
// K2a: logits[i] = b2 + sum(partial[i][:]); flag near-threshold tokens
// ---------------------------------------------------------------------------
__global__ __launch_bounds__(256) void k2a_logits(
    const float* __restrict__ partial,
    const float* __restrict__ b2,
    float* __restrict__ logits,
    int* __restrict__ flaglist,
    int* __restrict__ flagcnt)
{
  const int i = blockIdx.x * 256 + threadIdx.x;   // 0..16383
  const float* pp = partial + (size_t)i * NBLK;
  float lg = b2[0];
#pragma unroll
  for (int j = 0; j < NBLK; ++j) lg += pp[j];
  logits[i] = lg;
  if (fabsf(lg) < MARGIN) {
    int s = atomicAdd(flagcnt, 1);
    if (s < MAXFLAG) flaglist[s] = i;
  }
}

// ---------------------------------------------------------------------------
// K2b: exact f32 recompute of flagged rows, split 8x by column group.
// grid (8 cg, 64 fslot); partials to fixpart[f][cg] (deterministic).
// ---------------------------------------------------------------------------
__global__ __launch_bounds__(256) void k2b_fixup(
    const float* __restrict__ hidden,
    const float* __restrict__ W1,
    const float* __restrict__ b1,
    const float* __restrict__ W2,
    const int* __restrict__ flaglist,
    const int* __restrict__ flagcnt,
    float* __restrict__ fixpart)         // [MAXFLAG][8]
{
  const int cnt = min(*flagcnt, MAXFLAG);
  const int cg = blockIdx.x;             // 0..7
  __shared__ float hrow[D_];
  __shared__ float red[256];
  const int tid = threadIdx.x;
  const int col = cg * 256 + tid;
  for (int f = blockIdx.y; f < cnt; f += 64) {
    const int i = flaglist[f];
    const float* h = hidden + (size_t)i * D_;
    __syncthreads();
    *(f32x4_t*)&hrow[tid * 4] = *(const f32x4_t*)&h[tid * 4];
    __syncthreads();
    float acc = 0.f;
#pragma unroll 8
    for (int k = 0; k < D_; ++k)
      acc = fmaf(hrow[k], W1[(size_t)k * H_ + col], acc);
    red[tid] = fmaxf(acc + b1[col], 0.f) * W2[col];
    __syncthreads();
    for (int st = 128; st > 0; st >>= 1) {
      if (tid < st) red[tid] += red[tid + st];
      __syncthreads();
    }
    if (tid == 0) fixpart[f * 8 + cg] = red[0];
  }
}

// ---------------------------------------------------------------------------
// K2c: per-batch scan. Prologue applies fixup combine for this batch's
// flagged tokens; then lengths, hb bits, parallel prefix scan, segment
// starts, shortened mask, binomial NLL.
// ---------------------------------------------------------------------------
__global__ __launch_bounds__(256) void k2c_scan(
    float* __restrict__ logits,          // [8][2048] (fixed in-place)
    const float* __restrict__ mask,      // [8][2048]
    const float* __restrict__ target,    // [8]
    const float* __restrict__ b2,
    const float* __restrict__ fixpart,   // [MAXFLAG][8]
    const int* __restrict__ flaglist,
    const int* __restrict__ flagcnt,
    float* __restrict__ outmask,         // [8][2048]
    int*   __restrict__ seg,             // [8][2050]
    float* __restrict__ hdr)             // [8][4]
{
  const int b = blockIdx.x, tid = threadIdx.x;
  __shared__ float redf[256];
  __shared__ int tsum[256];
  __shared__ unsigned char hbs[L_];

  // fix-combine for this batch's flagged tokens (exact f32 logits)
  const int cnt = min(*flagcnt, MAXFLAG);
  for (int f = tid; f < cnt; f += 256) {
    const int i = flaglist[f];
    if ((i >> 11) == b) {
      float s = b2[0];
#pragma unroll
      for (int cg = 0; cg < 8; ++cg) s += fixpart[f * 8 + cg];
      logits[i] = s;
    }
  }
  // length (tree reduce); the first barrier also orders the fixup writes
  float lm = 0.f;
#pragma unroll
  for (int e = 0; e < 8; ++e) lm += mask[b * L_ + tid * 8 + e];
  redf[tid] = lm;
  __syncthreads();
  for (int s = 128; s > 0; s >>= 1) {
    if (tid < s) redf[tid] += redf[tid + s];
    __syncthreads();
  }
  const int length = (int)(redf[0] + 0.5f);

  int hloc[8];
  int lsum = 0;
#pragma unroll
  for (int e = 0; e < 8; ++e) {
    const int t = tid * 8 + e;
    const float lg = logits[b * L_ + t];
    int hb = (lg > 0.f) && (t < length);
    if (length < L_ && t == length - 1) hb = 1;
    hloc[e] = hb;
    hbs[t] = (unsigned char)hb;
    lsum += hb;
  }
  // parallel inclusive scan (Hillis-Steele) over per-thread sums
  tsum[tid] = lsum;
  __syncthreads();
  for (int off = 1; off < 256; off <<= 1) {
    int v = tsum[tid];
    int add = (tid >= off) ? tsum[tid - off] : 0;
    __syncthreads();
    tsum[tid] = v + add;
    __syncthreads();
  }
  const int ktot = tsum[255];

  int pre = tsum[tid] - lsum;            // exclusive prefix
  for (int e = 0; e < 8; ++e) {
    const int t = tid * 8 + e;
    if (t < length) {
      const bool st = (t == 0) || hbs[t - 1];
      if (st) seg[b * 2050 + pre] = t;
    }
    pre += hloc[e];
  }

#pragma unroll
  for (int e = 0; e < 8; ++e) {
    const int t = tid * 8 + e;
    outmask[b * L_ + t] = (t < ktot) ? 1.f : 0.f;
  }

  __syncthreads();
  if (tid == 0) {
    const int maxseg = ktot - (length > 0 ? (int)hbs[length - 1] : 0);
    seg[b * 2050 + maxseg + 1] = length;
    const float n = (float)length, k = (float)ktot;
    float p = target[b] / fmaxf(n, 1.f);
    p = fminf(fmaxf(p, 1e-6f), 1.f - 1e-6f);
    const float lp = lgammaf(n + 1.f) - lgammaf(k + 1.f) - lgammaf(n - k + 1.f)
                   + k * logf(p) + (n - k) * log1pf(-p);
    hdr[b * 4 + 0] = n;
    hdr[b * 4 + 1] = k;
    hdr[b * 4 + 2] = (float)maxseg;
    hdr[b * 4 + 3] = -lp;
  }
}

// ---------------------------------------------------------------------------
// K4b: pooled[b][s][:] = mean(hidden[b][st:en][:]) + PE[s][:]
// segment mean = edge rows + full 32-token chunk sums. Block 0 also emits
// the three scalars.
// ---------------------------------------------------------------------------
__global__ __launch_bounds__(256) void k4b_pool(
    const float* __restrict__ hidden,
    const float* __restrict__ chunkSum,
    const int*   __restrict__ seg,
    const float* __restrict__ hdr,
    float* __restrict__ pooled,
    float* __restrict__ out3)
{
  const int bid = blockIdx.x;
  const int b = bid >> 11, s = bid & 2047;
  const int tid = threadIdx.x;
  if (bid == 0 && tid == 0) {
    float s_lp = 0.f, s_k = 0.f, s_n = 0.f;
    for (int i = 0; i < B_; ++i) {
      s_n  += hdr[i * 4 + 0];
      s_k  += hdr[i * 4 + 1];
      s_lp += hdr[i * 4 + 3];
    }
    out3[0] = 10.f * (s_lp * 0.125f);
    out3[1] = s_k;
    out3[2] = s_n;
  }
  const int maxseg = (int)hdr[b * 4 + 2];

  float a0 = 0.f, a1 = 0.f, a2 = 0.f, a3 = 0.f;
  if (s <= maxseg) {
    const int st = seg[b * 2050 + s];
    const int en = seg[b * 2050 + s + 1];
    const float* hrow = hidden + (size_t)(b * L_) * D_ + tid * 4;
    const float* crow = chunkSum + (size_t)(b * NCH) * D_ + tid * 4;
    const int cs = (st + CHK - 1) / CHK;
    const int ce = en / CHK;
    if (cs >= ce) {
      for (int t = st; t < en; ++t) {
        const f32x4_t v = *(const f32x4_t*)(hrow + (size_t)t * D_);
        a0 += v.x; a1 += v.y; a2 += v.z; a3 += v.w;
      }
    } else {
      for (int t = st; t < cs * CHK; ++t) {
        const f32x4_t v = *(const f32x4_t*)(hrow + (size_t)t * D_);
        a0 += v.x; a1 += v.y; a2 += v.z; a3 += v.w;
      }
#pragma unroll 4
      for (int c = cs; c < ce; ++c) {
        const f32x4_t v = *(const f32x4_t*)(crow + (size_t)c * D_);
        a0 += v.x; a1 += v.y; a2 += v.z; a3 += v.w;
      }
      for (int t = ce * CHK; t < en; ++t) {
        const f32x4_t v = *(const f32x4_t*)(hrow + (size_t)t * D_);
        a0 += v.x; a1 += v.y; a2 += v.z; a3 += v.w;
      }
    }
    const float cnt = (float)(en - st);
    const float inv = 1.f / (cnt + 1e-9f);
    a0 *= inv; a1 *= inv; a2 *= inv; a3 *= inv;
  }
  // PE: ang = s * 10000^(-e) = s * exp2(-e * log2(10000)); fast HW sincos
  const float L2_10K = 13.287712379549449f;
  const float e0 = (float)(4 * tid)     * (1.f / 1024.f);
  const float e1 = (float)(4 * tid + 2) * (1.f / 1024.f);
  const float ang0 = (float)s * exp2f(-e0 * L2_10K);
  const float ang1 = (float)s * exp2f(-e1 * L2_10K);
  float s0, c0, s1, c1;
  __sincosf(ang0, &s0, &c0);
  __sincosf(ang1, &s1, &c1);
  f32x4_t o;
  o.x = a0 + s0; o.y = a1 + c0; o.z = a2 + s1; o.w = a3 + c1;
  *(f32x4_t*)(pooled + ((size_t)(b * L_ + s)) * D_ + tid * 4) = o;
}

// ---------------------------------------------------------------------------
extern "C" void kernel_launch(void* const* d_in, const int* in_sizes, int n_in,
                              void* d_out, int out_size, void* d_ws, size_t ws_size,
                              hipStream_t stream)
{
  (void)in_sizes; (void)n_in; (void)out_size; (void)ws_size;
  const float* hidden = (const float*)d_in[0];
  const float* amask  = (const float*)d_in[1];
  const float* target = (const float*)d_in[2];
  const float* W1     = (const float*)d_in[3];
  const float* b1     = (const float*)d_in[4];
  const float* W2     = (const float*)d_in[5];
  const float* b2     = (const float*)d_in[6];

  float* out     = (float*)d_out;
  float* pooled  = out;                       // 16777216 floats (written LAST)
  float* out3    = out + 16777216;
  float* outmask = out + 16777219;

  // Abf (16MB) + Bbf (2MB) live inside the pooled output region as scratch;
  // k4b fully overwrites pooled afterwards.
  unsigned char* Abf = (unsigned char*)out;               // 16 MB
  unsigned char* Bbf = (unsigned char*)(out + 8388608);   // 2 MB at byte offset 32MB

  char* ws = (char*)d_ws;
  float* partial  = (float*)ws;                      ws += (size_t)16384 * NBLK * 4;  // 512 KB
  int*   seg      = (int*)ws;                        ws += (size_t)B_ * 2050 * 4;
  float* hdr      = (float*)ws;                      ws += (size_t)B_ * 4 * 4;
  float* logits   = (float*)ws;                      ws += (size_t)B_ * L_ * 4;       // 64 KB
  int*   flaglist = (int*)ws;                        ws += (size_t)MAXFLAG * 4;
  int*   flagcnt  = (int*)ws;                        ws += 256;
  float* fixpart  = (float*)ws;                      ws += (size_t)MAXFLAG * 8 * 4;   // 32 KB
  float* chunkSum = (float*)ws;                      // 2 MB

  k0_pack<<<dim3(NK, 72), dim3(256), 0, stream>>>(hidden, W1, Abf, Bbf,
                                                  chunkSum, flagcnt);
  k1_gemm<<<dim3(512), dim3(512), 131072, stream>>>(Abf, Bbf, b1, W2, partial);
  k2a_logits<<<dim3(64), dim3(256), 0, stream>>>(partial, b2, logits, flaglist, flagcnt);
  k2b_fixup<<<dim3(8, 64), dim3(256), 0, stream>>>(hidden, W1, b1, W2,
                                                   flaglist, flagcnt, fixpart);
  k2c_scan<<<dim3(8), dim3(256), 0, stream>>>(logits, amask, target, b2, fixpart,
                                              flaglist, flagcnt, outmask, seg, hdr);
  k4b_pool<<<dim3(16384), dim3(256), 0, stream>>>(hidden, chunkSum, seg, hdr, pooled, out3);
}

// Round 14
// 100.097 us; speedup vs baseline: 3.5427x; 1.0732x over previous
//
#include <hip/hip_runtime.h>
#include <math.h>

#define B_   8
#define L_   2048
#define D_   1024
#define H_   2048
#define NBLK 8             // H_/256 N-tiles in the GEMM
#define CHK  32            // tokens per chunk in pooling pre-pass
#define NCH  (L_ / CHK)    // 64 chunks per batch item
#define BK   128           // MX fp8: 128 k per tile (one 16x16x128 MFMA step)
#define NK   (D_ / BK)     // 8 K-steps
#define MARGIN  0.5f       // |logit| below this -> exact f32 recompute
#define MAXFLAG 1024
#define BSCALE  16.0f      // W1 pre-scale (exact pow2), undone in epilogue
#define BUNSCALE 0.0625f

typedef float  f32x4_t  __attribute__((ext_vector_type(4)));
typedef int    i32x4_t  __attribute__((ext_vector_type(4)));
typedef int    i32x8_t  __attribute__((ext_vector_type(8)));

// Swizzled fp8 tile images: tile = 256 rows x BK(128) fp8 = 32KB, 128B/row.
// Row r = 8 chunks of 16B; logical chunk c (k=c*16..c*16+15) stored at
// physical chunk c ^ (r&7)  [G4 fix: 128B stride makes bank = f(chunk) only,
// so the row-XOR spreads a quad-group's lanes across all 8 bank-quads].
// k1 frag (row, lk) = chunks 2lk, 2lk+1 -> two ds_read_b128 per frag.
#define TILE_BYTES 32768

__device__ inline int pk4_fp8(float a, float b, float c, float d) {
  int w = __builtin_amdgcn_cvt_pk_fp8_f32(a, b, 0, false);
  w = __builtin_amdgcn_cvt_pk_fp8_f32(c, d, w, true);
  return w;
}

// ---------------------------------------------------------------------------
// K0 (merged): y<64: hidden -> Abf fp8 tiles + 32-token chunk sums
//              y>=64: W1 -> Bbf fp8 tiles (x16); zeroes flagcnt
// Processed in two 64-dim halves to keep registers bounded.
// ---------------------------------------------------------------------------
__global__ __launch_bounds__(256) void k0_pack(
    const float* __restrict__ A,      // [16384][1024]
    const float* __restrict__ W1,     // [1024][2048]
    unsigned char* __restrict__ Abf,  // [64 mt][8 kt] tiles of 32KB
    unsigned char* __restrict__ Bbf,  // [8 nt][8 kt] tiles of 32KB
    float* __restrict__ chunkSum,     // [8][NCH][1024]
    int* __restrict__ flagcnt)
{
  __shared__ float scratch[256][33];
  const int kt = blockIdx.x;   // 0..7
  const int yy = blockIdx.y;   // 0..71
  const int r  = threadIdx.x;  // 0..255

  if (yy >= 64) {              // ---- B path ----
    const int nt = yy - 64;
    if (kt == 0 && nt == 0 && r == 0) *flagcnt = 0;
    const float* src = W1 + (size_t)(kt * BK) * H_ + nt * 256 + r;
    char* dst = (char*)Bbf + ((size_t)(nt * 8 + kt)) * TILE_BYTES + r * 128;
#pragma unroll
    for (int h = 0; h < 2; ++h) {
      float v[64];
#pragma unroll
      for (int j = 0; j < 64; ++j)
        v[j] = src[(size_t)(h * 64 + j) * H_] * BSCALE;
#pragma unroll
      for (int q = 0; q < 4; ++q) {
        const int c = h * 4 + q;
        i32x4_t o;
        o[0] = pk4_fp8(v[q*16+ 0], v[q*16+ 1], v[q*16+ 2], v[q*16+ 3]);
        o[1] = pk4_fp8(v[q*16+ 4], v[q*16+ 5], v[q*16+ 6], v[q*16+ 7]);
        o[2] = pk4_fp8(v[q*16+ 8], v[q*16+ 9], v[q*16+10], v[q*16+11]);
        o[3] = pk4_fp8(v[q*16+12], v[q*16+13], v[q*16+14], v[q*16+15]);
        *(i32x4_t*)(dst + ((c ^ (r & 7)) << 4)) = o;
      }
    }
    return;
  }

  // ---- A path ----
  const int mt = yy;
  const float* src = A + (size_t)(mt * 256 + r) * D_ + kt * BK;
  char* dst = (char*)Abf + ((size_t)(mt * 8 + kt)) * TILE_BYTES + r * 128;
  const int ch = r >> 5, j = r & 31;
  const int b  = mt >> 3;
  const int cg = (mt & 7) * 8 + ch;
#pragma unroll
  for (int h = 0; h < 2; ++h) {
    float v[64];
#pragma unroll
    for (int q = 0; q < 16; ++q) {
      f32x4_t x = *(const f32x4_t*)(src + h * 64 + q * 4);
      v[q*4] = x.x; v[q*4+1] = x.y; v[q*4+2] = x.z; v[q*4+3] = x.w;
    }
#pragma unroll
    for (int q = 0; q < 4; ++q) {
      const int c = h * 4 + q;
      i32x4_t o;
      o[0] = pk4_fp8(v[q*16+ 0], v[q*16+ 1], v[q*16+ 2], v[q*16+ 3]);
      o[1] = pk4_fp8(v[q*16+ 4], v[q*16+ 5], v[q*16+ 6], v[q*16+ 7]);
      o[2] = pk4_fp8(v[q*16+ 8], v[q*16+ 9], v[q*16+10], v[q*16+11]);
      o[3] = pk4_fp8(v[q*16+12], v[q*16+13], v[q*16+14], v[q*16+15]);
      *(i32x4_t*)(dst + ((c ^ (r & 7)) << 4)) = o;
    }
    // chunk sums: two 32-dim sub-halves through LDS transpose
#pragma unroll
    for (int sub = 0; sub < 2; ++sub) {
      __syncthreads();
#pragma unroll
      for (int q = 0; q < 8; ++q)
        *(f32x4_t*)&scratch[r][q * 4] = *(const f32x4_t*)&v[sub * 32 + q * 4];
      __syncthreads();
      float s = 0.f;
#pragma unroll
      for (int q = 0; q < 32; ++q) s += scratch[ch * 32 + q][j];
      chunkSum[((size_t)(b * NCH + cg)) * D_ + kt * BK + h * 64 + sub * 32 + j] = s;
    }
  }
}

// ---------------------------------------------------------------------------
// K1: MX-fp8 GEMM 256x256 tile, BK=128, 8 waves (2Mx4N, wave tile 128x64),
// mfma_scale_f32_16x16x128_f8f6f4 with UNIT scales (E8M0 127 = 2^0) ->
// plain fp8 math at 2x rate, 4x FLOP/instr. Ring-2 LDS (2 x 64KB), depth-1
// prefetch via global_load_lds(16B), counted vmcnt(8) (never 0 mid-loop).
// Frag read: two ds_read_b128/lane, row-XOR swizzle (G4) -> conflict-light.
// Epilogue: relu(C/16 + b1) . W2 row-reduce -> partial[m][nt].
// ---------------------------------------------------------------------------
__global__ __launch_bounds__(512, 2) void k1_gemm(
    const unsigned char* __restrict__ Abf,
    const unsigned char* __restrict__ Bbf,
    const float* __restrict__ b1,
    const float* __restrict__ W2,
    float* __restrict__ partial)    // [16384][NBLK]
{
  extern __shared__ __align__(16) unsigned char lds[];   // 131072 bytes

  const int tid  = threadIdx.x;           // 0..511
  // XCD-bijective swizzle (512 blocks % 8 == 0)
  const int wg   = (blockIdx.x & 7) * 64 + (blockIdx.x >> 3);
  const int mt   = wg >> 3;               // 0..63
  const int nt   = wg & 7;                // 0..7
  const int m0   = mt * 256;
  const int n0   = nt * 256;
  const int lane = tid & 63;
  const int wave = tid >> 6;              // 0..7
  const int wr = wave >> 2, wc = wave & 3;
  const int lr = lane & 15, lk = lane >> 4;

  const char* aT = (const char*)Abf + ((size_t)mt * NK) * TILE_BYTES;
  const char* bT = (const char*)Bbf + ((size_t)nt * NK) * TILE_BYTES;

  f32x4_t acc[8][4];
#pragma unroll
  for (int m = 0; m < 8; ++m)
#pragma unroll
    for (int n = 0; n < 4; ++n)
      acc[m][n] = (f32x4_t){0.f, 0.f, 0.f, 0.f};

  // stage K-tile t (A 32KB + B 32KB) into ring buffer buf: 8 x 16B per thread
  auto stage = [&](int t, int buf) {
    const char* ga = aT + (size_t)t * TILE_BYTES;
    const char* gb = bT + (size_t)t * TILE_BYTES;
    unsigned char* lb = lds + buf * 65536;
#pragma unroll
    for (int jj = 0; jj < 8; ++jj) {
      const int i = jj * 512 + tid;        // 0..4095 16B-chunks
      const char* g = (jj < 4) ? ga + i * 16 : gb + (i - 2048) * 16;
      __builtin_amdgcn_global_load_lds(
          (const __attribute__((address_space(1))) void*)g,
          (__attribute__((address_space(3))) void*)(lb + i * 16),
          16, 0, 0);
    }
  };

  stage(0, 0);
  for (int t = 0; t < NK; ++t) {
    __builtin_amdgcn_s_barrier();        // WAR: buf[(t+1)&1] reads all retired
    if (t + 1 < NK) {
      stage(t + 1, (t + 1) & 1);
      asm volatile("s_waitcnt vmcnt(8)" ::: "memory");   // stage(t) landed
    } else {
      asm volatile("s_waitcnt vmcnt(0)" ::: "memory");
    }
    __builtin_amdgcn_s_barrier();        // all waves' stage(t) shares visible
    asm volatile("" ::: "memory");       // no LDS reads hoist above barrier

    const char* sA = (const char*)(lds + (t & 1) * 65536);
    const char* sB = sA + 32768;

    // B frags: col = lane&15, k-block = lane>>4 (32 consecutive k per lane)
    i32x8_t bfr[4];
#pragma unroll
    for (int n = 0; n < 4; ++n) {
      const int c = wc * 64 + n * 16 + lr;
      const char* base = sB + c * 128;
      i32x4_t lo = *(const i32x4_t*)(base + (((2 * lk)     ^ (c & 7)) << 4));
      i32x4_t hi = *(const i32x4_t*)(base + (((2 * lk + 1) ^ (c & 7)) << 4));
      bfr[n][0] = lo[0]; bfr[n][1] = lo[1]; bfr[n][2] = lo[2]; bfr[n][3] = lo[3];
      bfr[n][4] = hi[0]; bfr[n][5] = hi[1]; bfr[n][6] = hi[2]; bfr[n][7] = hi[3];
    }
#pragma unroll
    for (int mh = 0; mh < 2; ++mh) {
      i32x8_t afr[4];
#pragma unroll
      for (int i = 0; i < 4; ++i) {
        const int rr = wr * 128 + (mh * 4 + i) * 16 + lr;
        const char* base = sA + rr * 128;
        i32x4_t lo = *(const i32x4_t*)(base + (((2 * lk)     ^ (rr & 7)) << 4));
        i32x4_t hi = *(const i32x4_t*)(base + (((2 * lk + 1) ^ (rr & 7)) << 4));
        afr[i][0] = lo[0]; afr[i][1] = lo[1]; afr[i][2] = lo[2]; afr[i][3] = lo[3];
        afr[i][4] = hi[0]; afr[i][5] = hi[1]; afr[i][6] = hi[2]; afr[i][7] = hi[3];
      }
#pragma unroll
      for (int i = 0; i < 4; ++i)
#pragma unroll
        for (int n = 0; n < 4; ++n)
          acc[mh * 4 + i][n] = __builtin_amdgcn_mfma_scale_f32_16x16x128_f8f6f4(
              afr[i], bfr[n], acc[mh * 4 + i][n],
              0 /*cbsz: fp8 e4m3*/, 0 /*blgp: fp8 e4m3*/,
              0, 127 /*scaleA: E8M0 1.0*/, 0, 127 /*scaleB*/);
    }
  }

  // ---- epilogue: relu(C/16 + b1) * W2, reduce over cols, write partial ----
  // (C/D layout of scaled op is shape-determined: col = lane&15, verified)
  float rs[8][4];
#pragma unroll
  for (int m = 0; m < 8; ++m)
#pragma unroll
    for (int rg = 0; rg < 4; ++rg) rs[m][rg] = 0.f;

#pragma unroll
  for (int n = 0; n < 4; ++n) {
    const int jg = n0 + wc * 64 + n * 16 + lr;
    const float w2v = W2[jg];
    const float b1v = b1[jg];
#pragma unroll
    for (int m = 0; m < 8; ++m)
#pragma unroll
      for (int rg = 0; rg < 4; ++rg) {
        float v = acc[m][n][rg] * BUNSCALE + b1v;
        rs[m][rg] += fmaxf(v, 0.f) * w2v;
      }
  }
#pragma unroll
  for (int m = 0; m < 8; ++m)
#pragma unroll
    for (int rg = 0; rg < 4; ++rg) {
      float v = rs[m][rg];
      v += __shfl_xor(v, 1);
      v += __shfl_xor(v, 2);
      v += __shfl_xor(v, 4);
      v += __shfl_xor(v, 8);
      rs[m][rg] = v;                      // col-sum of this wave's 64-col slab
    }
  __syncthreads();                        // all frag reads done; alias lds
  float (*part_lds)[4] = (float(*)[4])lds;   // [256][4]
  if (lr == 0) {
#pragma unroll
    for (int m = 0; m < 8; ++m)
#pragma unroll
      for (int rg = 0; rg < 4; ++rg)
        part_lds[wr * 128 + m * 16 + lk * 4 + rg][wc] = rs[m][rg];
  }
  __syncthreads();
  if (tid < 256) {
    const float sum = part_lds[tid][0] + part_lds[tid][1]
                    + part_lds[tid][2] + part_lds[tid][3];
    partial[(size_t)(m0 + tid) * NBLK + nt] = sum;
  }
}

// ---------------------------------------------------------------------------
// K2a: logits[i] = b2 + sum(partial[i][:]); flag near-threshold tokens
// ---------------------------------------------------------------------------
__global__ __launch_bounds__(256) void k2a_logits(
    const float* __restrict__ partial,
    const float* __restrict__ b2,
    float* __restrict__ logits,
    int* __restrict__ flaglist,
    int* __restrict__ flagcnt)
{
  const int i = blockIdx.x * 256 + threadIdx.x;   // 0..16383
  const float* pp = partial + (size_t)i * NBLK;
  float lg = b2[0];
#pragma unroll
  for (int j = 0; j < NBLK; ++j) lg += pp[j];
  logits[i] = lg;
  if (fabsf(lg) < MARGIN) {
    int s = atomicAdd(flagcnt, 1);
    if (s < MAXFLAG) flaglist[s] = i;
  }
}

// ---------------------------------------------------------------------------
// K2b: exact f32 recompute of flagged rows, split 8x by column group.
// ---------------------------------------------------------------------------
__global__ __launch_bounds__(256) void k2b_fixup(
    const float* __restrict__ hidden,
    const float* __restrict__ W1,
    const float* __restrict__ b1,
    const float* __restrict__ W2,
    const int* __restrict__ flaglist,
    const int* __restrict__ flagcnt,
    float* __restrict__ fixpart)         // [MAXFLAG][8]
{
  const int cnt = min(*flagcnt, MAXFLAG);
  const int cg = blockIdx.x;             // 0..7
  __shared__ float hrow[D_];
  __shared__ float red[256];
  const int tid = threadIdx.x;
  const int col = cg * 256 + tid;
  for (int f = blockIdx.y; f < cnt; f += 64) {
    const int i = flaglist[f];
    const float* h = hidden + (size_t)i * D_;
    __syncthreads();
    *(f32x4_t*)&hrow[tid * 4] = *(const f32x4_t*)&h[tid * 4];
    __syncthreads();
    float acc = 0.f;
#pragma unroll 8
    for (int k = 0; k < D_; ++k)
      acc = fmaf(hrow[k], W1[(size_t)k * H_ + col], acc);
    red[tid] = fmaxf(acc + b1[col], 0.f) * W2[col];
    __syncthreads();
    for (int st = 128; st > 0; st >>= 1) {
      if (tid < st) red[tid] += red[tid + st];
      __syncthreads();
    }
    if (tid == 0) fixpart[f * 8 + cg] = red[0];
  }
}

// ---------------------------------------------------------------------------
// K2c: per-batch scan. Prologue applies fixup combine; then lengths, hb bits,
// parallel prefix scan, segment starts, shortened mask, binomial NLL.
// ---------------------------------------------------------------------------
__global__ __launch_bounds__(256) void k2c_scan(
    float* __restrict__ logits,          // [8][2048] (fixed in-place)
    const float* __restrict__ mask,      // [8][2048]
    const float* __restrict__ target,    // [8]
    const float* __restrict__ b2,
    const float* __restrict__ fixpart,   // [MAXFLAG][8]
    const int* __restrict__ flaglist,
    const int* __restrict__ flagcnt,
    float* __restrict__ outmask,         // [8][2048]
    int*   __restrict__ seg,             // [8][2050]
    float* __restrict__ hdr)             // [8][4]
{
  const int b = blockIdx.x, tid = threadIdx.x;
  __shared__ float redf[256];
  __shared__ int tsum[256];
  __shared__ unsigned char hbs[L_];

  const int cnt = min(*flagcnt, MAXFLAG);
  for (int f = tid; f < cnt; f += 256) {
    const int i = flaglist[f];
    if ((i >> 11) == b) {
      float s = b2[0];
#pragma unroll
      for (int cg = 0; cg < 8; ++cg) s += fixpart[f * 8 + cg];
      logits[i] = s;
    }
  }
  float lm = 0.f;
#pragma unroll
  for (int e = 0; e < 8; ++e) lm += mask[b * L_ + tid * 8 + e];
  redf[tid] = lm;
  __syncthreads();
  for (int s = 128; s > 0; s >>= 1) {
    if (tid < s) redf[tid] += redf[tid + s];
    __syncthreads();
  }
  const int length = (int)(redf[0] + 0.5f);

  int hloc[8];
  int lsum = 0;
#pragma unroll
  for (int e = 0; e < 8; ++e) {
    const int t = tid * 8 + e;
    const float lg = logits[b * L_ + t];
    int hb = (lg > 0.f) && (t < length);
    if (length < L_ && t == length - 1) hb = 1;
    hloc[e] = hb;
    hbs[t] = (unsigned char)hb;
    lsum += hb;
  }
  tsum[tid] = lsum;
  __syncthreads();
  for (int off = 1; off < 256; off <<= 1) {
    int v = tsum[tid];
    int add = (tid >= off) ? tsum[tid - off] : 0;
    __syncthreads();
    tsum[tid] = v + add;
    __syncthreads();
  }
  const int ktot = tsum[255];

  int pre = tsum[tid] - lsum;            // exclusive prefix
  for (int e = 0; e < 8; ++e) {
    const int t = tid * 8 + e;
    if (t < length) {
      const bool st = (t == 0) || hbs[t - 1];
      if (st) seg[b * 2050 + pre] = t;
    }
    pre += hloc[e];
  }

#pragma unroll
  for (int e = 0; e < 8; ++e) {
    const int t = tid * 8 + e;
    outmask[b * L_ + t] = (t < ktot) ? 1.f : 0.f;
  }

  __syncthreads();
  if (tid == 0) {
    const int maxseg = ktot - (length > 0 ? (int)hbs[length - 1] : 0);
    seg[b * 2050 + maxseg + 1] = length;
    const float n = (float)length, k = (float)ktot;
    float p = target[b] / fmaxf(n, 1.f);
    p = fminf(fmaxf(p, 1e-6f), 1.f - 1e-6f);
    const float lp = lgammaf(n + 1.f) - lgammaf(k + 1.f) - lgammaf(n - k + 1.f)
                   + k * logf(p) + (n - k) * log1pf(-p);
    hdr[b * 4 + 0] = n;
    hdr[b * 4 + 1] = k;
    hdr[b * 4 + 2] = (float)maxseg;
    hdr[b * 4 + 3] = -lp;
  }
}

// ---------------------------------------------------------------------------
// K4b: pooled[b][s][:] = mean(hidden[b][st:en][:]) + PE[s][:]
// ---------------------------------------------------------------------------
__global__ __launch_bounds__(256) void k4b_pool(
    const float* __restrict__ hidden,
    const float* __restrict__ chunkSum,
    const int*   __restrict__ seg,
    const float* __restrict__ hdr,
    float* __restrict__ pooled,
    float* __restrict__ out3)
{
  const int bid = blockIdx.x;
  const int b = bid >> 11, s = bid & 2047;
  const int tid = threadIdx.x;
  if (bid == 0 && tid == 0) {
    float s_lp = 0.f, s_k = 0.f, s_n = 0.f;
    for (int i = 0; i < B_; ++i) {
      s_n  += hdr[i * 4 + 0];
      s_k  += hdr[i * 4 + 1];
      s_lp += hdr[i * 4 + 3];
    }
    out3[0] = 10.f * (s_lp * 0.125f);
    out3[1] = s_k;
    out3[2] = s_n;
  }
  const int maxseg = (int)hdr[b * 4 + 2];

  float a0 = 0.f, a1 = 0.f, a2 = 0.f, a3 = 0.f;
  if (s <= maxseg) {
    const int st = seg[b * 2050 + s];
    const int en = seg[b * 2050 + s + 1];
    const float* hrow = hidden + (size_t)(b * L_) * D_ + tid * 4;
    const float* crow = chunkSum + (size_t)(b * NCH) * D_ + tid * 4;
    const int cs = (st + CHK - 1) / CHK;
    const int ce = en / CHK;
    if (cs >= ce) {
      for (int t = st; t < en; ++t) {
        const f32x4_t v = *(const f32x4_t*)(hrow + (size_t)t * D_);
        a0 += v.x; a1 += v.y; a2 += v.z; a3 += v.w;
      }
    } else {
      for (int t = st; t < cs * CHK; ++t) {
        const f32x4_t v = *(const f32x4_t*)(hrow + (size_t)t * D_);
        a0 += v.x; a1 += v.y; a2 += v.z; a3 += v.w;
      }
#pragma unroll 4
      for (int c = cs; c < ce; ++c) {
        const f32x4_t v = *(const f32x4_t*)(crow + (size_t)c * D_);
        a0 += v.x; a1 += v.y; a2 += v.z; a3 += v.w;
      }
      for (int t = ce * CHK; t < en; ++t) {
        const f32x4_t v = *(const f32x4_t*)(hrow + (size_t)t * D_);
        a0 += v.x; a1 += v.y; a2 += v.z; a3 += v.w;
      }
    }
    const float cnt = (float)(en - st);
    const float inv = 1.f / (cnt + 1e-9f);
    a0 *= inv; a1 *= inv; a2 *= inv; a3 *= inv;
  }
  const float L2_10K = 13.287712379549449f;
  const float e0 = (float)(4 * tid)     * (1.f / 1024.f);
  const float e1 = (float)(4 * tid + 2) * (1.f / 1024.f);
  const float ang0 = (float)s * exp2f(-e0 * L2_10K);
  const float ang1 = (float)s * exp2f(-e1 * L2_10K);
  float s0, c0, s1, c1;
  __sincosf(ang0, &s0, &c0);
  __sincosf(ang1, &s1, &c1);
  f32x4_t o;
  o.x = a0 + s0; o.y = a1 + c0; o.z = a2 + s1; o.w = a3 + c1;
  *(f32x4_t*)(pooled + ((size_t)(b * L_ + s)) * D_ + tid * 4) = o;
}

// ---------------------------------------------------------------------------
extern "C" void kernel_launch(void* const* d_in, const int* in_sizes, int n_in,
                              void* d_out, int out_size, void* d_ws, size_t ws_size,
                              hipStream_t stream)
{
  (void)in_sizes; (void)n_in; (void)out_size; (void)ws_size;
  const float* hidden = (const float*)d_in[0];
  const float* amask  = (const float*)d_in[1];
  const float* target = (const float*)d_in[2];
  const float* W1     = (const float*)d_in[3];
  const float* b1     = (const float*)d_in[4];
  const float* W2     = (const float*)d_in[5];
  const float* b2     = (const float*)d_in[6];

  float* out     = (float*)d_out;
  float* pooled  = out;                       // 16777216 floats (written LAST)
  float* out3    = out + 16777216;
  float* outmask = out + 16777219;

  // Abf (16MB) + Bbf (2MB) live inside the pooled output region as scratch;
  // k4b fully overwrites pooled afterwards.
  unsigned char* Abf = (unsigned char*)out;               // 16 MB
  unsigned char* Bbf = (unsigned char*)(out + 8388608);   // 2 MB at byte offset 32MB

  char* ws = (char*)d_ws;
  float* partial  = (float*)ws;                      ws += (size_t)16384 * NBLK * 4;  // 512 KB
  int*   seg      = (int*)ws;                        ws += (size_t)B_ * 2050 * 4;
  float* hdr      = (float*)ws;                      ws += (size_t)B_ * 4 * 4;
  float* logits   = (float*)ws;                      ws += (size_t)B_ * L_ * 4;       // 64 KB
  int*   flaglist = (int*)ws;                        ws += (size_t)MAXFLAG * 4;
  int*   flagcnt  = (int*)ws;                        ws += 256;
  float* fixpart  = (float*)ws;                      ws += (size_t)MAXFLAG * 8 * 4;   // 32 KB
  float* chunkSum = (float*)ws;                      // 2 MB

  k0_pack<<<dim3(NK, 72), dim3(256), 0, stream>>>(hidden, W1, Abf, Bbf,
                                                  chunkSum, flagcnt);
  k1_gemm<<<dim3(512), dim3(512), 131072, stream>>>(Abf, Bbf, b1, W2, partial);
  k2a_logits<<<dim3(64), dim3(256), 0, stream>>>(partial, b2, logits, flaglist, flagcnt);
  k2b_fixup<<<dim3(8, 64), dim3(256), 0, stream>>>(hidden, W1, b1, W2,
                                                   flaglist, flagcnt, fixpart);
  k2c_scan<<<dim3(8), dim3(256), 0, stream>>>(logits, amask, target, b2, fixpart,
                                              flaglist, flagcnt, outmask, seg, hdr);
  k4b_pool<<<dim3(16384), dim3(256), 0, stream>>>(hidden, chunkSum, seg, hdr, pooled, out3);
}

// Round 15
// 99.717 us; speedup vs baseline: 3.5562x; 1.0038x over previous
//
#include <hip/hip_runtime.h>
#include <math.h>

#define B_   8
#define L_   2048
#define D_   1024
#define H_   2048
#define NBLK 8             // H_/256 N-tiles in the GEMM
#define CHK  32            // tokens per chunk in pooling pre-pass
#define NCH  (L_ / CHK)    // 64 chunks per batch item
#define BK   128           // MX fp8: 128 k per tile (one 16x16x128 MFMA step)
#define NK   (D_ / BK)     // 8 K-steps
#define MARGIN  0.5f       // |logit| below this -> exact f32 recompute
#define MAXFLAG 1024
#define BSCALE  16.0f      // W1 pre-scale (exact pow2), undone in epilogue
#define BUNSCALE 0.0625f

typedef float  f32x4_t  __attribute__((ext_vector_type(4)));
typedef int    i32x4_t  __attribute__((ext_vector_type(4)));
typedef int    i32x8_t  __attribute__((ext_vector_type(8)));

// Tile = 32KB = TWO 16KB sub-tiles (lo/hi), each 256 rows x 64B (4 chunks).
// Lane (lr,lk) owns k = lk*32..+31: chunk lk of sub-lo holds k = lk*32..+15,
// chunk lk of sub-hi holds k = lk*32+16..+31; chunk g stored at physical
// g ^ ((r>>1)&3) with 64B row stride — the EXACT round-9 address pattern
// that measured 0 LDS bank conflicts (round-14's 128B-stride layout hit 3.15M).
#define TILE_BYTES 32768
#define SUB_BYTES  16384

__device__ inline int pk4_fp8(float a, float b, float c, float d) {
  int w = __builtin_amdgcn_cvt_pk_fp8_f32(a, b, 0, false);
  w = __builtin_amdgcn_cvt_pk_fp8_f32(c, d, w, true);
  return w;
}

// ---------------------------------------------------------------------------
// K0 (merged): y<64: hidden -> Abf fp8 tiles + 32-token chunk sums
//              y>=64: W1 -> Bbf fp8 tiles (x16); zeroes flagcnt
// Processed in two 64-dim halves to keep registers bounded.
// ---------------------------------------------------------------------------
__global__ __launch_bounds__(256) void k0_pack(
    const float* __restrict__ A,      // [16384][1024]
    const float* __restrict__ W1,     // [1024][2048]
    unsigned char* __restrict__ Abf,  // [64 mt][8 kt] tiles of 32KB
    unsigned char* __restrict__ Bbf,  // [8 nt][8 kt] tiles of 32KB
    float* __restrict__ chunkSum,     // [8][NCH][1024]
    int* __restrict__ flagcnt)
{
  __shared__ float scratch[256][33];
  const int kt = blockIdx.x;   // 0..7
  const int yy = blockIdx.y;   // 0..71
  const int r  = threadIdx.x;  // 0..255
  const int sw = ((r >> 1) & 3);

  if (yy >= 64) {              // ---- B path ----
    const int nt = yy - 64;
    if (kt == 0 && nt == 0 && r == 0) *flagcnt = 0;
    const float* src = W1 + (size_t)(kt * BK) * H_ + nt * 256 + r;
    char* dstLo = (char*)Bbf + ((size_t)(nt * 8 + kt)) * TILE_BYTES + r * 64;
    char* dstHi = dstLo + SUB_BYTES;
#pragma unroll
    for (int h = 0; h < 2; ++h) {
      float v[64];
#pragma unroll
      for (int j = 0; j < 64; ++j)
        v[j] = src[(size_t)(h * 64 + j) * H_] * BSCALE;
#pragma unroll
      for (int gl = 0; gl < 2; ++gl) {
        const int g = h * 2 + gl;
        i32x4_t lo, hi;
        lo[0] = pk4_fp8(v[gl*32+ 0], v[gl*32+ 1], v[gl*32+ 2], v[gl*32+ 3]);
        lo[1] = pk4_fp8(v[gl*32+ 4], v[gl*32+ 5], v[gl*32+ 6], v[gl*32+ 7]);
        lo[2] = pk4_fp8(v[gl*32+ 8], v[gl*32+ 9], v[gl*32+10], v[gl*32+11]);
        lo[3] = pk4_fp8(v[gl*32+12], v[gl*32+13], v[gl*32+14], v[gl*32+15]);
        hi[0] = pk4_fp8(v[gl*32+16], v[gl*32+17], v[gl*32+18], v[gl*32+19]);
        hi[1] = pk4_fp8(v[gl*32+20], v[gl*32+21], v[gl*32+22], v[gl*32+23]);
        hi[2] = pk4_fp8(v[gl*32+24], v[gl*32+25], v[gl*32+26], v[gl*32+27]);
        hi[3] = pk4_fp8(v[gl*32+28], v[gl*32+29], v[gl*32+30], v[gl*32+31]);
        *(i32x4_t*)(dstLo + ((g ^ sw) << 4)) = lo;
        *(i32x4_t*)(dstHi + ((g ^ sw) << 4)) = hi;
      }
    }
    return;
  }

  // ---- A path ----
  const int mt = yy;
  const float* src = A + (size_t)(mt * 256 + r) * D_ + kt * BK;
  char* dstLo = (char*)Abf + ((size_t)(mt * 8 + kt)) * TILE_BYTES + r * 64;
  char* dstHi = dstLo + SUB_BYTES;
  const int ch = r >> 5, j = r & 31;
  const int b  = mt >> 3;
  const int cg = (mt & 7) * 8 + ch;
#pragma unroll
  for (int h = 0; h < 2; ++h) {
    float v[64];
#pragma unroll
    for (int q = 0; q < 16; ++q) {
      f32x4_t x = *(const f32x4_t*)(src + h * 64 + q * 4);
      v[q*4] = x.x; v[q*4+1] = x.y; v[q*4+2] = x.z; v[q*4+3] = x.w;
    }
#pragma unroll
    for (int gl = 0; gl < 2; ++gl) {
      const int g = h * 2 + gl;
      i32x4_t lo, hi;
      lo[0] = pk4_fp8(v[gl*32+ 0], v[gl*32+ 1], v[gl*32+ 2], v[gl*32+ 3]);
      lo[1] = pk4_fp8(v[gl*32+ 4], v[gl*32+ 5], v[gl*32+ 6], v[gl*32+ 7]);
      lo[2] = pk4_fp8(v[gl*32+ 8], v[gl*32+ 9], v[gl*32+10], v[gl*32+11]);
      lo[3] = pk4_fp8(v[gl*32+12], v[gl*32+13], v[gl*32+14], v[gl*32+15]);
      hi[0] = pk4_fp8(v[gl*32+16], v[gl*32+17], v[gl*32+18], v[gl*32+19]);
      hi[1] = pk4_fp8(v[gl*32+20], v[gl*32+21], v[gl*32+22], v[gl*32+23]);
      hi[2] = pk4_fp8(v[gl*32+24], v[gl*32+25], v[gl*32+26], v[gl*32+27]);
      hi[3] = pk4_fp8(v[gl*32+28], v[gl*32+29], v[gl*32+30], v[gl*32+31]);
      *(i32x4_t*)(dstLo + ((g ^ sw) << 4)) = lo;
      *(i32x4_t*)(dstHi + ((g ^ sw) << 4)) = hi;
    }
    // chunk sums: two 32-dim sub-halves through LDS transpose
#pragma unroll
    for (int sub = 0; sub < 2; ++sub) {
      __syncthreads();
#pragma unroll
      for (int q = 0; q < 8; ++q)
        *(f32x4_t*)&scratch[r][q * 4] = *(const f32x4_t*)&v[sub * 32 + q * 4];
      __syncthreads();
      float s = 0.f;
#pragma unroll
      for (int q = 0; q < 32; ++q) s += scratch[ch * 32 + q][j];
      chunkSum[((size_t)(b * NCH + cg)) * D_ + kt * BK + h * 64 + sub * 32 + j] = s;
    }
  }
}

// ---------------------------------------------------------------------------
// K1: MX-fp8 GEMM 256x256 tile, BK=128, 8 waves (2Mx4N, wave tile 128x64),
// mfma_scale_f32_16x16x128_f8f6f4 with UNIT scales (E8M0 127 = 2^0).
// Ring-2 LDS (2 x 64KB), depth-1 prefetch via global_load_lds(16B),
// counted vmcnt(8) (never 0 mid-loop). Frag read: two ds_read_b128/lane at
// 64B stride + round-9 XOR (0-conflict pattern).
// Epilogue: relu(C/16 + b1) . W2 row-reduce -> partial[m][nt].
// ---------------------------------------------------------------------------
__global__ __launch_bounds__(512, 2) void k1_gemm(
    const unsigned char* __restrict__ Abf,
    const unsigned char* __restrict__ Bbf,
    const float* __restrict__ b1,
    const float* __restrict__ W2,
    float* __restrict__ partial)    // [16384][NBLK]
{
  extern __shared__ __align__(16) unsigned char lds[];   // 131072 bytes

  const int tid  = threadIdx.x;           // 0..511
  // XCD-bijective swizzle (512 blocks % 8 == 0)
  const int wg   = (blockIdx.x & 7) * 64 + (blockIdx.x >> 3);
  const int mt   = wg >> 3;               // 0..63
  const int nt   = wg & 7;                // 0..7
  const int m0   = mt * 256;
  const int n0   = nt * 256;
  const int lane = tid & 63;
  const int wave = tid >> 6;              // 0..7
  const int wr = wave >> 2, wc = wave & 3;
  const int lr = lane & 15, lk = lane >> 4;

  const char* aT = (const char*)Abf + ((size_t)mt * NK) * TILE_BYTES;
  const char* bT = (const char*)Bbf + ((size_t)nt * NK) * TILE_BYTES;

  f32x4_t acc[8][4];
#pragma unroll
  for (int m = 0; m < 8; ++m)
#pragma unroll
    for (int n = 0; n < 4; ++n)
      acc[m][n] = (f32x4_t){0.f, 0.f, 0.f, 0.f};

  // stage K-tile t (A 32KB + B 32KB) into ring buffer buf: 8 x 16B per thread
  auto stage = [&](int t, int buf) {
    const char* ga = aT + (size_t)t * TILE_BYTES;
    const char* gb = bT + (size_t)t * TILE_BYTES;
    unsigned char* lb = lds + buf * 65536;
#pragma unroll
    for (int jj = 0; jj < 8; ++jj) {
      const int i = jj * 512 + tid;        // 0..4095 16B-chunks
      const char* g = (jj < 4) ? ga + i * 16 : gb + (i - 2048) * 16;
      __builtin_amdgcn_global_load_lds(
          (const __attribute__((address_space(1))) void*)g,
          (__attribute__((address_space(3))) void*)(lb + i * 16),
          16, 0, 0);
    }
  };

  stage(0, 0);
  for (int t = 0; t < NK; ++t) {
    __builtin_amdgcn_s_barrier();        // WAR: buf[(t+1)&1] reads all retired
    if (t + 1 < NK) {
      stage(t + 1, (t + 1) & 1);
      asm volatile("s_waitcnt vmcnt(8)" ::: "memory");   // stage(t) landed
    } else {
      asm volatile("s_waitcnt vmcnt(0)" ::: "memory");
    }
    __builtin_amdgcn_s_barrier();        // all waves' stage(t) shares visible
    asm volatile("" ::: "memory");       // no LDS reads hoist above barrier

    const char* sA = (const char*)(lds + (t & 1) * 65536);
    const char* sB = sA + TILE_BYTES;

    // frag: lo 16B (k = lk*32..+15) from sub-lo, hi 16B (+16..+31) from sub-hi
    i32x8_t bfr[4];
#pragma unroll
    for (int n = 0; n < 4; ++n) {
      const int c = wc * 64 + n * 16 + lr;
      const int off = c * 64 + ((lk ^ ((c >> 1) & 3)) << 4);
      i32x4_t lo = *(const i32x4_t*)(sB + off);
      i32x4_t hi = *(const i32x4_t*)(sB + SUB_BYTES + off);
      bfr[n][0] = lo[0]; bfr[n][1] = lo[1]; bfr[n][2] = lo[2]; bfr[n][3] = lo[3];
      bfr[n][4] = hi[0]; bfr[n][5] = hi[1]; bfr[n][6] = hi[2]; bfr[n][7] = hi[3];
    }
#pragma unroll
    for (int mh = 0; mh < 2; ++mh) {
      i32x8_t afr[4];
#pragma unroll
      for (int i = 0; i < 4; ++i) {
        const int rr = wr * 128 + (mh * 4 + i) * 16 + lr;
        const int off = rr * 64 + ((lk ^ ((rr >> 1) & 3)) << 4);
        i32x4_t lo = *(const i32x4_t*)(sA + off);
        i32x4_t hi = *(const i32x4_t*)(sA + SUB_BYTES + off);
        afr[i][0] = lo[0]; afr[i][1] = lo[1]; afr[i][2] = lo[2]; afr[i][3] = lo[3];
        afr[i][4] = hi[0]; afr[i][5] = hi[1]; afr[i][6] = hi[2]; afr[i][7] = hi[3];
      }
#pragma unroll
      for (int i = 0; i < 4; ++i)
#pragma unroll
        for (int n = 0; n < 4; ++n)
          acc[mh * 4 + i][n] = __builtin_amdgcn_mfma_scale_f32_16x16x128_f8f6f4(
              afr[i], bfr[n], acc[mh * 4 + i][n],
              0 /*cbsz: fp8 e4m3*/, 0 /*blgp: fp8 e4m3*/,
              0, 127 /*scaleA: E8M0 1.0*/, 0, 127 /*scaleB*/);
    }
  }

  // ---- epilogue: relu(C/16 + b1) * W2, reduce over cols, write partial ----
  float rs[8][4];
#pragma unroll
  for (int m = 0; m < 8; ++m)
#pragma unroll
    for (int rg = 0; rg < 4; ++rg) rs[m][rg] = 0.f;

#pragma unroll
  for (int n = 0; n < 4; ++n) {
    const int jg = n0 + wc * 64 + n * 16 + lr;   // C/D: col = lane&15
    const float w2v = W2[jg];
    const float b1v = b1[jg];
#pragma unroll
    for (int m = 0; m < 8; ++m)
#pragma unroll
      for (int rg = 0; rg < 4; ++rg) {
        float v = acc[m][n][rg] * BUNSCALE + b1v;
        rs[m][rg] += fmaxf(v, 0.f) * w2v;
      }
  }
#pragma unroll
  for (int m = 0; m < 8; ++m)
#pragma unroll
    for (int rg = 0; rg < 4; ++rg) {
      float v = rs[m][rg];
      v += __shfl_xor(v, 1);
      v += __shfl_xor(v, 2);
      v += __shfl_xor(v, 4);
      v += __shfl_xor(v, 8);
      rs[m][rg] = v;                      // col-sum of this wave's 64-col slab
    }
  __syncthreads();                        // all frag reads done; alias lds
  float (*part_lds)[4] = (float(*)[4])lds;   // [256][4]
  if (lr == 0) {
#pragma unroll
    for (int m = 0; m < 8; ++m)
#pragma unroll
      for (int rg = 0; rg < 4; ++rg)
        part_lds[wr * 128 + m * 16 + lk * 4 + rg][wc] = rs[m][rg];
  }
  __syncthreads();
  if (tid < 256) {
    const float sum = part_lds[tid][0] + part_lds[tid][1]
                    + part_lds[tid][2] + part_lds[tid][3];
    partial[(size_t)(m0 + tid) * NBLK + nt] = sum;
  }
}

// ---------------------------------------------------------------------------
// K2a: logits[i] = b2 + sum(partial[i][:]); flag near-threshold tokens
// ---------------------------------------------------------------------------
__global__ __launch_bounds__(256) void k2a_logits(
    const float* __restrict__ partial,
    const float* __restrict__ b2,
    float* __restrict__ logits,
    int* __restrict__ flaglist,
    int* __restrict__ flagcnt)
{
  const int i = blockIdx.x * 256 + threadIdx.x;   // 0..16383
  const float* pp = partial + (size_t)i * NBLK;
  float lg = b2[0];
#pragma unroll
  for (int j = 0; j < NBLK; ++j) lg += pp[j];
  logits[i] = lg;
  if (fabsf(lg) < MARGIN) {
    int s = atomicAdd(flagcnt, 1);
    if (s < MAXFLAG) flaglist[s] = i;
  }
}

// ---------------------------------------------------------------------------
// K2b: exact f32 recompute of flagged rows, split 8x by column group.
// ---------------------------------------------------------------------------
__global__ __launch_bounds__(256) void k2b_fixup(
    const float* __restrict__ hidden,
    const float* __restrict__ W1,
    const float* __restrict__ b1,
    const float* __restrict__ W2,
    const int* __restrict__ flaglist,
    const int* __restrict__ flagcnt,
    float* __restrict__ fixpart)         // [MAXFLAG][8]
{
  const int cnt = min(*flagcnt, MAXFLAG);
  const int cg = blockIdx.x;             // 0..7
  __shared__ float hrow[D_];
  __shared__ float red[256];
  const int tid = threadIdx.x;
  const int col = cg * 256 + tid;
  for (int f = blockIdx.y; f < cnt; f += 64) {
    const int i = flaglist[f];
    const float* h = hidden + (size_t)i * D_;
    __syncthreads();
    *(f32x4_t*)&hrow[tid * 4] = *(const f32x4_t*)&h[tid * 4];
    __syncthreads();
    float acc = 0.f;
#pragma unroll 8
    for (int k = 0; k < D_; ++k)
      acc = fmaf(hrow[k], W1[(size_t)k * H_ + col], acc);
    red[tid] = fmaxf(acc + b1[col], 0.f) * W2[col];
    __syncthreads();
    for (int st = 128; st > 0; st >>= 1) {
      if (tid < st) red[tid] += red[tid + st];
      __syncthreads();
    }
    if (tid == 0) fixpart[f * 8 + cg] = red[0];
  }
}

// ---------------------------------------------------------------------------
// K2c: per-batch scan. Prologue applies fixup combine; then lengths, hb bits,
// parallel prefix scan, segment starts, shortened mask, binomial NLL.
// ---------------------------------------------------------------------------
__global__ __launch_bounds__(256) void k2c_scan(
    float* __restrict__ logits,          // [8][2048] (fixed in-place)
    const float* __restrict__ mask,      // [8][2048]
    const float* __restrict__ target,    // [8]
    const float* __restrict__ b2,
    const float* __restrict__ fixpart,   // [MAXFLAG][8]
    const int* __restrict__ flaglist,
    const int* __restrict__ flagcnt,
    float* __restrict__ outmask,         // [8][2048]
    int*   __restrict__ seg,             // [8][2050]
    float* __restrict__ hdr)             // [8][4]
{
  const int b = blockIdx.x, tid = threadIdx.x;
  __shared__ float redf[256];
  __shared__ int tsum[256];
  __shared__ unsigned char hbs[L_];

  const int cnt = min(*flagcnt, MAXFLAG);
  for (int f = tid; f < cnt; f += 256) {
    const int i = flaglist[f];
    if ((i >> 11) == b) {
      float s = b2[0];
#pragma unroll
      for (int cg = 0; cg < 8; ++cg) s += fixpart[f * 8 + cg];
      logits[i] = s;
    }
  }
  float lm = 0.f;
#pragma unroll
  for (int e = 0; e < 8; ++e) lm += mask[b * L_ + tid * 8 + e];
  redf[tid] = lm;
  __syncthreads();
  for (int s = 128; s > 0; s >>= 1) {
    if (tid < s) redf[tid] += redf[tid + s];
    __syncthreads();
  }
  const int length = (int)(redf[0] + 0.5f);

  int hloc[8];
  int lsum = 0;
#pragma unroll
  for (int e = 0; e < 8; ++e) {
    const int t = tid * 8 + e;
    const float lg = logits[b * L_ + t];
    int hb = (lg > 0.f) && (t < length);
    if (length < L_ && t == length - 1) hb = 1;
    hloc[e] = hb;
    hbs[t] = (unsigned char)hb;
    lsum += hb;
  }
  tsum[tid] = lsum;
  __syncthreads();
  for (int off = 1; off < 256; off <<= 1) {
    int v = tsum[tid];
    int add = (tid >= off) ? tsum[tid - off] : 0;
    __syncthreads();
    tsum[tid] = v + add;
    __syncthreads();
  }
  const int ktot = tsum[255];

  int pre = tsum[tid] - lsum;            // exclusive prefix
  for (int e = 0; e < 8; ++e) {
    const int t = tid * 8 + e;
    if (t < length) {
      const bool st = (t == 0) || hbs[t - 1];
      if (st) seg[b * 2050 + pre] = t;
    }
    pre += hloc[e];
  }

#pragma unroll
  for (int e = 0; e < 8; ++e) {
    const int t = tid * 8 + e;
    outmask[b * L_ + t] = (t < ktot) ? 1.f : 0.f;
  }

  __syncthreads();
  if (tid == 0) {
    const int maxseg = ktot - (length > 0 ? (int)hbs[length - 1] : 0);
    seg[b * 2050 + maxseg + 1] = length;
    const float n = (float)length, k = (float)ktot;
    float p = target[b] / fmaxf(n, 1.f);
    p = fminf(fmaxf(p, 1e-6f), 1.f - 1e-6f);
    const float lp = lgammaf(n + 1.f) - lgammaf(k + 1.f) - lgammaf(n - k + 1.f)
                   + k * logf(p) + (n - k) * log1pf(-p);
    hdr[b * 4 + 0] = n;
    hdr[b * 4 + 1] = k;
    hdr[b * 4 + 2] = (float)maxseg;
    hdr[b * 4 + 3] = -lp;
  }
}

// ---------------------------------------------------------------------------
// K4b: pooled[b][s][:] = mean(hidden[b][st:en][:]) + PE[s][:]
// ---------------------------------------------------------------------------
__global__ __launch_bounds__(256) void k4b_pool(
    const float* __restrict__ hidden,
    const float* __restrict__ chunkSum,
    const int*   __restrict__ seg,
    const float* __restrict__ hdr,
    float* __restrict__ pooled,
    float* __restrict__ out3)
{
  const int bid = blockIdx.x;
  const int b = bid >> 11, s = bid & 2047;
  const int tid = threadIdx.x;
  if (bid == 0 && tid == 0) {
    float s_lp = 0.f, s_k = 0.f, s_n = 0.f;
    for (int i = 0; i < B_; ++i) {
      s_n  += hdr[i * 4 + 0];
      s_k  += hdr[i * 4 + 1];
      s_lp += hdr[i * 4 + 3];
    }
    out3[0] = 10.f * (s_lp * 0.125f);
    out3[1] = s_k;
    out3[2] = s_n;
  }
  const int maxseg = (int)hdr[b * 4 + 2];

  float a0 = 0.f, a1 = 0.f, a2 = 0.f, a3 = 0.f;
  if (s <= maxseg) {
    const int st = seg[b * 2050 + s];
    const int en = seg[b * 2050 + s + 1];
    const float* hrow = hidden + (size_t)(b * L_) * D_ + tid * 4;
    const float* crow = chunkSum + (size_t)(b * NCH) * D_ + tid * 4;
    const int cs = (st + CHK - 1) / CHK;
    const int ce = en / CHK;
    if (cs >= ce) {
      for (int t = st; t < en; ++t) {
        const f32x4_t v = *(const f32x4_t*)(hrow + (size_t)t * D_);
        a0 += v.x; a1 += v.y; a2 += v.z; a3 += v.w;
      }
    } else {
      for (int t = st; t < cs * CHK; ++t) {
        const f32x4_t v = *(const f32x4_t*)(hrow + (size_t)t * D_);
        a0 += v.x; a1 += v.y; a2 += v.z; a3 += v.w;
      }
#pragma unroll 4
      for (int c = cs; c < ce; ++c) {
        const f32x4_t v = *(const f32x4_t*)(crow + (size_t)c * D_);
        a0 += v.x; a1 += v.y; a2 += v.z; a3 += v.w;
      }
      for (int t = ce * CHK; t < en; ++t) {
        const f32x4_t v = *(const f32x4_t*)(hrow + (size_t)t * D_);
        a0 += v.x; a1 += v.y; a2 += v.z; a3 += v.w;
      }
    }
    const float cnt = (float)(en - st);
    const float inv = 1.f / (cnt + 1e-9f);
    a0 *= inv; a1 *= inv; a2 *= inv; a3 *= inv;
  }
  const float L2_10K = 13.287712379549449f;
  const float e0 = (float)(4 * tid)     * (1.f / 1024.f);
  const float e1 = (float)(4 * tid + 2) * (1.f / 1024.f);
  const float ang0 = (float)s * exp2f(-e0 * L2_10K);
  const float ang1 = (float)s * exp2f(-e1 * L2_10K);
  float s0, c0, s1, c1;
  __sincosf(ang0, &s0, &c0);
  __sincosf(ang1, &s1, &c1);
  f32x4_t o;
  o.x = a0 + s0; o.y = a1 + c0; o.z = a2 + s1; o.w = a3 + c1;
  *(f32x4_t*)(pooled + ((size_t)(b * L_ + s)) * D_ + tid * 4) = o;
}

// ---------------------------------------------------------------------------
extern "C" void kernel_launch(void* const* d_in, const int* in_sizes, int n_in,
                              void* d_out, int out_size, void* d_ws, size_t ws_size,
                              hipStream_t stream)
{
  (void)in_sizes; (void)n_in; (void)out_size; (void)ws_size;
  const float* hidden = (const float*)d_in[0];
  const float* amask  = (const float*)d_in[1];
  const float* target = (const float*)d_in[2];
  const float* W1     = (const float*)d_in[3];
  const float* b1     = (const float*)d_in[4];
  const float* W2     = (const float*)d_in[5];
  const float* b2     = (const float*)d_in[6];

  float* out     = (float*)d_out;
  float* pooled  = out;                       // 16777216 floats (written LAST)
  float* out3    = out + 16777216;
  float* outmask = out + 16777219;

  // Abf (16MB) + Bbf (2MB) live inside the pooled output region as scratch;
  // k4b fully overwrites pooled afterwards.
  unsigned char* Abf = (unsigned char*)out;               // 16 MB
  unsigned char* Bbf = (unsigned char*)(out + 8388608);   // 2 MB at byte offset 32MB

  char* ws = (char*)d_ws;
  float* partial  = (float*)ws;                      ws += (size_t)16384 * NBLK * 4;  // 512 KB
  int*   seg      = (int*)ws;                        ws += (size_t)B_ * 2050 * 4;
  float* hdr      = (float*)ws;                      ws += (size_t)B_ * 4 * 4;
  float* logits   = (float*)ws;                      ws += (size_t)B_ * L_ * 4;       // 64 KB
  int*   flaglist = (int*)ws;                        ws += (size_t)MAXFLAG * 4;
  int*   flagcnt  = (int*)ws;                        ws += 256;
  float* fixpart  = (float*)ws;                      ws += (size_t)MAXFLAG * 8 * 4;   // 32 KB
  float* chunkSum = (float*)ws;                      // 2 MB

  k0_pack<<<dim3(NK, 72), dim3(256), 0, stream>>>(hidden, W1, Abf, Bbf,
                                                  chunkSum, flagcnt);
  k1_gemm<<<dim3(512), dim3(512), 131072, stream>>>(Abf, Bbf, b1, W2, partial);
  k2a_logits<<<dim3(64), dim3(256), 0, stream>>>(partial, b2, logits, flaglist, flagcnt);
  k2b_fixup<<<dim3(8, 64), dim3(256), 0, stream>>>(hidden, W1, b1, W2,
                                                   flaglist, flagcnt, fixpart);
  k2c_scan<<<dim3(8), dim3(256), 0, stream>>>(logits, amask, target, b2, fixpart,
                                              flaglist, flagcnt, outmask, seg, hdr);
  k4b_pool<<<dim3(16384), dim3(256), 0, stream>>>(hidden, chunkSum, seg, hdr, pooled, out3);
}

// Round 16
// 99.497 us; speedup vs baseline: 3.5640x; 1.0022x over previous
//
#include <hip/hip_runtime.h>
#include <math.h>

#define B_   8
#define L_   2048
#define D_   1024
#define H_   2048
#define NBLK 8             // H_/256 N-tiles in the GEMM
#define CHK  32            // tokens per chunk in pooling pre-pass
#define NCH  (L_ / CHK)    // 64 chunks per batch item
#define BK   128           // MX fp8: 128 k per tile (one 16x16x128 MFMA step)
#define NK   (D_ / BK)     // 8 K-steps
#define MARGIN  0.5f       // |logit| below this -> exact f32 recompute
#define MAXFLAG 1024
#define FBATCH  4          // flags recomputed per W1 pass in k2b
#define BSCALE  16.0f      // W1 pre-scale (exact pow2), undone in epilogue
#define BUNSCALE 0.0625f

typedef float  f32x2_t  __attribute__((ext_vector_type(2)));
typedef float  f32x4_t  __attribute__((ext_vector_type(4)));
typedef int    i32x4_t  __attribute__((ext_vector_type(4)));
typedef int    i32x8_t  __attribute__((ext_vector_type(8)));

// Tile = 32KB = TWO 16KB sub-tiles (lo/hi), each 256 rows x 64B (4 chunks).
// Lane (lr,lk) owns k = lk*32..+31: chunk lk of sub-lo holds k = lk*32..+15,
// chunk lk of sub-hi holds k = lk*32+16..+31; chunk g stored at physical
// g ^ ((r>>1)&3) with 64B row stride — the round-9 0-conflict pattern.
#define TILE_BYTES 32768
#define SUB_BYTES  16384

__device__ inline int pk4_fp8(float a, float b, float c, float d) {
  int w = __builtin_amdgcn_cvt_pk_fp8_f32(a, b, 0, false);
  w = __builtin_amdgcn_cvt_pk_fp8_f32(c, d, w, true);
  return w;
}

// ---------------------------------------------------------------------------
// K0 (merged): y<64: hidden -> Abf fp8 tiles + 32-token chunk sums
//              y>=64: W1 -> Bbf fp8 tiles (x16); zeroes flagcnt
// ---------------------------------------------------------------------------
__global__ __launch_bounds__(256) void k0_pack(
    const float* __restrict__ A,      // [16384][1024]
    const float* __restrict__ W1,     // [1024][2048]
    unsigned char* __restrict__ Abf,  // [64 mt][8 kt] tiles of 32KB
    unsigned char* __restrict__ Bbf,  // [8 nt][8 kt] tiles of 32KB
    float* __restrict__ chunkSum,     // [8][NCH][1024]
    int* __restrict__ flagcnt)
{
  __shared__ float scratch[256][33];
  const int kt = blockIdx.x;   // 0..7
  const int yy = blockIdx.y;   // 0..71
  const int r  = threadIdx.x;  // 0..255
  const int sw = ((r >> 1) & 3);

  if (yy >= 64) {              // ---- B path ----
    const int nt = yy - 64;
    if (kt == 0 && nt == 0 && r == 0) *flagcnt = 0;
    const float* src = W1 + (size_t)(kt * BK) * H_ + nt * 256 + r;
    char* dstLo = (char*)Bbf + ((size_t)(nt * 8 + kt)) * TILE_BYTES + r * 64;
    char* dstHi = dstLo + SUB_BYTES;
#pragma unroll
    for (int h = 0; h < 2; ++h) {
      float v[64];
#pragma unroll
      for (int j = 0; j < 64; ++j)
        v[j] = src[(size_t)(h * 64 + j) * H_] * BSCALE;
#pragma unroll
      for (int gl = 0; gl < 2; ++gl) {
        const int g = h * 2 + gl;
        i32x4_t lo, hi;
        lo[0] = pk4_fp8(v[gl*32+ 0], v[gl*32+ 1], v[gl*32+ 2], v[gl*32+ 3]);
        lo[1] = pk4_fp8(v[gl*32+ 4], v[gl*32+ 5], v[gl*32+ 6], v[gl*32+ 7]);
        lo[2] = pk4_fp8(v[gl*32+ 8], v[gl*32+ 9], v[gl*32+10], v[gl*32+11]);
        lo[3] = pk4_fp8(v[gl*32+12], v[gl*32+13], v[gl*32+14], v[gl*32+15]);
        hi[0] = pk4_fp8(v[gl*32+16], v[gl*32+17], v[gl*32+18], v[gl*32+19]);
        hi[1] = pk4_fp8(v[gl*32+20], v[gl*32+21], v[gl*32+22], v[gl*32+23]);
        hi[2] = pk4_fp8(v[gl*32+24], v[gl*32+25], v[gl*32+26], v[gl*32+27]);
        hi[3] = pk4_fp8(v[gl*32+28], v[gl*32+29], v[gl*32+30], v[gl*32+31]);
        *(i32x4_t*)(dstLo + ((g ^ sw) << 4)) = lo;
        *(i32x4_t*)(dstHi + ((g ^ sw) << 4)) = hi;
      }
    }
    return;
  }

  // ---- A path ----
  const int mt = yy;
  const float* src = A + (size_t)(mt * 256 + r) * D_ + kt * BK;
  char* dstLo = (char*)Abf + ((size_t)(mt * 8 + kt)) * TILE_BYTES + r * 64;
  char* dstHi = dstLo + SUB_BYTES;
  const int ch = r >> 5, j = r & 31;
  const int b  = mt >> 3;
  const int cg = (mt & 7) * 8 + ch;
#pragma unroll
  for (int h = 0; h < 2; ++h) {
    float v[64];
#pragma unroll
    for (int q = 0; q < 16; ++q) {
      f32x4_t x = *(const f32x4_t*)(src + h * 64 + q * 4);
      v[q*4] = x.x; v[q*4+1] = x.y; v[q*4+2] = x.z; v[q*4+3] = x.w;
    }
#pragma unroll
    for (int gl = 0; gl < 2; ++gl) {
      const int g = h * 2 + gl;
      i32x4_t lo, hi;
      lo[0] = pk4_fp8(v[gl*32+ 0], v[gl*32+ 1], v[gl*32+ 2], v[gl*32+ 3]);
      lo[1] = pk4_fp8(v[gl*32+ 4], v[gl*32+ 5], v[gl*32+ 6], v[gl*32+ 7]);
      lo[2] = pk4_fp8(v[gl*32+ 8], v[gl*32+ 9], v[gl*32+10], v[gl*32+11]);
      lo[3] = pk4_fp8(v[gl*32+12], v[gl*32+13], v[gl*32+14], v[gl*32+15]);
      hi[0] = pk4_fp8(v[gl*32+16], v[gl*32+17], v[gl*32+18], v[gl*32+19]);
      hi[1] = pk4_fp8(v[gl*32+20], v[gl*32+21], v[gl*32+22], v[gl*32+23]);
      hi[2] = pk4_fp8(v[gl*32+24], v[gl*32+25], v[gl*32+26], v[gl*32+27]);
      hi[3] = pk4_fp8(v[gl*32+28], v[gl*32+29], v[gl*32+30], v[gl*32+31]);
      *(i32x4_t*)(dstLo + ((g ^ sw) << 4)) = lo;
      *(i32x4_t*)(dstHi + ((g ^ sw) << 4)) = hi;
    }
    // chunk sums: two 32-dim sub-halves through LDS transpose
#pragma unroll
    for (int sub = 0; sub < 2; ++sub) {
      __syncthreads();
#pragma unroll
      for (int q = 0; q < 8; ++q)
        *(f32x4_t*)&scratch[r][q * 4] = *(const f32x4_t*)&v[sub * 32 + q * 4];
      __syncthreads();
      float s = 0.f;
#pragma unroll
      for (int q = 0; q < 32; ++q) s += scratch[ch * 32 + q][j];
      chunkSum[((size_t)(b * NCH + cg)) * D_ + kt * BK + h * 64 + sub * 32 + j] = s;
    }
  }
}

// ---------------------------------------------------------------------------
// K1: MX-fp8 GEMM 256x256 tile, BK=128, 8 waves (2Mx4N, wave tile 128x64),
// mfma_scale_f32_16x16x128_f8f6f4 with UNIT scales (E8M0 127 = 2^0).
// Ring-2 LDS (2 x 64KB), depth-1 prefetch via global_load_lds(16B),
// counted vmcnt(8) (never 0 mid-loop). Frag read: two ds_read_b128/lane at
// 64B stride + round-9 XOR (0-conflict pattern).
// Epilogue: relu(C/16 + b1) . W2 row-reduce -> partial[m][nt].
// ---------------------------------------------------------------------------
__global__ __launch_bounds__(512, 2) void k1_gemm(
    const unsigned char* __restrict__ Abf,
    const unsigned char* __restrict__ Bbf,
    const float* __restrict__ b1,
    const float* __restrict__ W2,
    float* __restrict__ partial)    // [16384][NBLK]
{
  extern __shared__ __align__(16) unsigned char lds[];   // 131072 bytes

  const int tid  = threadIdx.x;           // 0..511
  // XCD-bijective swizzle (512 blocks % 8 == 0)
  const int wg   = (blockIdx.x & 7) * 64 + (blockIdx.x >> 3);
  const int mt   = wg >> 3;               // 0..63
  const int nt   = wg & 7;                // 0..7
  const int m0   = mt * 256;
  const int n0   = nt * 256;
  const int lane = tid & 63;
  const int wave = tid >> 6;              // 0..7
  const int wr = wave >> 2, wc = wave & 3;
  const int lr = lane & 15, lk = lane >> 4;

  const char* aT = (const char*)Abf + ((size_t)mt * NK) * TILE_BYTES;
  const char* bT = (const char*)Bbf + ((size_t)nt * NK) * TILE_BYTES;

  f32x4_t acc[8][4];
#pragma unroll
  for (int m = 0; m < 8; ++m)
#pragma unroll
    for (int n = 0; n < 4; ++n)
      acc[m][n] = (f32x4_t){0.f, 0.f, 0.f, 0.f};

  // stage K-tile t (A 32KB + B 32KB) into ring buffer buf: 8 x 16B per thread
  auto stage = [&](int t, int buf) {
    const char* ga = aT + (size_t)t * TILE_BYTES;
    const char* gb = bT + (size_t)t * TILE_BYTES;
    unsigned char* lb = lds + buf * 65536;
#pragma unroll
    for (int jj = 0; jj < 8; ++jj) {
      const int i = jj * 512 + tid;        // 0..4095 16B-chunks
      const char* g = (jj < 4) ? ga + i * 16 : gb + (i - 2048) * 16;
      __builtin_amdgcn_global_load_lds(
          (const __attribute__((address_space(1))) void*)g,
          (__attribute__((address_space(3))) void*)(lb + i * 16),
          16, 0, 0);
    }
  };

  stage(0, 0);
  for (int t = 0; t < NK; ++t) {
    __builtin_amdgcn_s_barrier();        // WAR: buf[(t+1)&1] reads all retired
    if (t + 1 < NK) {
      stage(t + 1, (t + 1) & 1);
      asm volatile("s_waitcnt vmcnt(8)" ::: "memory");   // stage(t) landed
    } else {
      asm volatile("s_waitcnt vmcnt(0)" ::: "memory");
    }
    __builtin_amdgcn_s_barrier();        // all waves' stage(t) shares visible
    asm volatile("" ::: "memory");       // no LDS reads hoist above barrier

    const char* sA = (const char*)(lds + (t & 1) * 65536);
    const char* sB = sA + TILE_BYTES;

    // frag: lo 16B (k = lk*32..+15) from sub-lo, hi 16B (+16..+31) from sub-hi
    i32x8_t bfr[4];
#pragma unroll
    for (int n = 0; n < 4; ++n) {
      const int c = wc * 64 + n * 16 + lr;
      const int off = c * 64 + ((lk ^ ((c >> 1) & 3)) << 4);
      i32x4_t lo = *(const i32x4_t*)(sB + off);
      i32x4_t hi = *(const i32x4_t*)(sB + SUB_BYTES + off);
      bfr[n][0] = lo[0]; bfr[n][1] = lo[1]; bfr[n][2] = lo[2]; bfr[n][3] = lo[3];
      bfr[n][4] = hi[0]; bfr[n][5] = hi[1]; bfr[n][6] = hi[2]; bfr[n][7] = hi[3];
    }
#pragma unroll
    for (int mh = 0; mh < 2; ++mh) {
      i32x8_t afr[4];
#pragma unroll
      for (int i = 0; i < 4; ++i) {
        const int rr = wr * 128 + (mh * 4 + i) * 16 + lr;
        const int off = rr * 64 + ((lk ^ ((rr >> 1) & 3)) << 4);
        i32x4_t lo = *(const i32x4_t*)(sA + off);
        i32x4_t hi = *(const i32x4_t*)(sA + SUB_BYTES + off);
        afr[i][0] = lo[0]; afr[i][1] = lo[1]; afr[i][2] = lo[2]; afr[i][3] = lo[3];
        afr[i][4] = hi[0]; afr[i][5] = hi[1]; afr[i][6] = hi[2]; afr[i][7] = hi[3];
      }
#pragma unroll
      for (int i = 0; i < 4; ++i)
#pragma unroll
        for (int n = 0; n < 4; ++n)
          acc[mh * 4 + i][n] = __builtin_amdgcn_mfma_scale_f32_16x16x128_f8f6f4(
              afr[i], bfr[n], acc[mh * 4 + i][n],
              0 /*cbsz: fp8 e4m3*/, 0 /*blgp: fp8 e4m3*/,
              0, 127 /*scaleA: E8M0 1.0*/, 0, 127 /*scaleB*/);
    }
  }

  // ---- epilogue: relu(C/16 + b1) * W2, reduce over cols, write partial ----
  float rs[8][4];
#pragma unroll
  for (int m = 0; m < 8; ++m)
#pragma unroll
    for (int rg = 0; rg < 4; ++rg) rs[m][rg] = 0.f;

#pragma unroll
  for (int n = 0; n < 4; ++n) {
    const int jg = n0 + wc * 64 + n * 16 + lr;   // C/D: col = lane&15
    const float w2v = W2[jg];
    const float b1v = b1[jg];
#pragma unroll
    for (int m = 0; m < 8; ++m)
#pragma unroll
      for (int rg = 0; rg < 4; ++rg) {
        float v = acc[m][n][rg] * BUNSCALE + b1v;
        rs[m][rg] += fmaxf(v, 0.f) * w2v;
      }
  }
#pragma unroll
  for (int m = 0; m < 8; ++m)
#pragma unroll
    for (int rg = 0; rg < 4; ++rg) {
      float v = rs[m][rg];
      v += __shfl_xor(v, 1);
      v += __shfl_xor(v, 2);
      v += __shfl_xor(v, 4);
      v += __shfl_xor(v, 8);
      rs[m][rg] = v;                      // col-sum of this wave's 64-col slab
    }
  __syncthreads();                        // all frag reads done; alias lds
  float (*part_lds)[4] = (float(*)[4])lds;   // [256][4]
  if (lr == 0) {
#pragma unroll
    for (int m = 0; m < 8; ++m)
#pragma unroll
      for (int rg = 0; rg < 4; ++rg)
        part_lds[wr * 128 + m * 16 + lk * 4 + rg][wc] = rs[m][rg];
  }
  __syncthreads();
  if (tid < 256) {
    const float sum = part_lds[tid][0] + part_lds[tid][1]
                    + part_lds[tid][2] + part_lds[tid][3];
    partial[(size_t)(m0 + tid) * NBLK + nt] = sum;
  }
}

// ---------------------------------------------------------------------------
// K2a: logits[i] = b2 + sum(partial[i][:]); flag near-threshold tokens.
// Block 0 also fills the PE frequency LUT (tid-only dependent).
// ---------------------------------------------------------------------------
__global__ __launch_bounds__(256) void k2a_logits(
    const float* __restrict__ partial,
    const float* __restrict__ b2,
    float* __restrict__ logits,
    int* __restrict__ flaglist,
    int* __restrict__ flagcnt,
    float* __restrict__ freq)            // [512] 10000^(-2p/1024)
{
  const int tid = threadIdx.x;
  if (blockIdx.x == 0) {
    const float L2_10K = 13.287712379549449f;
    freq[tid]       = exp2f(-((float)(2 * tid)        * (1.f / 1024.f)) * L2_10K);
    freq[tid + 256] = exp2f(-((float)(2 * (tid + 256)) * (1.f / 1024.f)) * L2_10K);
  }
  const int i = blockIdx.x * 256 + tid;   // 0..16383
  const float* pp = partial + (size_t)i * NBLK;
  float lg = b2[0];
#pragma unroll
  for (int j = 0; j < NBLK; ++j) lg += pp[j];
  logits[i] = lg;
  if (fabsf(lg) < MARGIN) {
    int s = atomicAdd(flagcnt, 1);
    if (s < MAXFLAG) flaglist[s] = i;
  }
}

// ---------------------------------------------------------------------------
// K2b: exact f32 recompute of flagged rows, split 8x by column group,
// FBATCH(4) flags per W1 pass (4 hidden rows staged in LDS, broadcast reads)
// -> W1 traffic / 4 vs one-flag-per-pass. Deterministic (no atomics).
// ---------------------------------------------------------------------------
__global__ __launch_bounds__(256) void k2b_fixup(
    const float* __restrict__ hidden,
    const float* __restrict__ W1,
    const float* __restrict__ b1,
    const float* __restrict__ W2,
    const int* __restrict__ flaglist,
    const int* __restrict__ flagcnt,
    float* __restrict__ fixpart)         // [MAXFLAG][8]
{
  const int cnt = min(*flagcnt, MAXFLAG);
  const int cg = blockIdx.x;             // 0..7
  __shared__ float hrow[FBATCH][D_];
  __shared__ float red[256];
  const int tid = threadIdx.x;
  const int col = cg * 256 + tid;
  for (int f0 = blockIdx.y * FBATCH; f0 < cnt; f0 += 16 * FBATCH) {
    const int nb = min(FBATCH, cnt - f0);
    __syncthreads();                      // prior pass's hrow reads retired
    for (int ff = 0; ff < nb; ++ff) {
      const float* h = hidden + (size_t)flaglist[f0 + ff] * D_;
      *(f32x4_t*)&hrow[ff][tid * 4] = *(const f32x4_t*)&h[tid * 4];
    }
    __syncthreads();
    float acc[FBATCH] = {0.f, 0.f, 0.f, 0.f};
    for (int k = 0; k < D_; ++k) {
      const float w = W1[(size_t)k * H_ + col];
#pragma unroll
      for (int ff = 0; ff < FBATCH; ++ff)
        acc[ff] = fmaf(hrow[ff][k], w, acc[ff]);   // hrow broadcast (bank-free)
    }
    for (int ff = 0; ff < nb; ++ff) {
      red[tid] = fmaxf(acc[ff] + b1[col], 0.f) * W2[col];
      __syncthreads();
      for (int st = 128; st > 0; st >>= 1) {
        if (tid < st) red[tid] += red[tid + st];
        __syncthreads();
      }
      if (tid == 0) fixpart[(f0 + ff) * 8 + cg] = red[0];
      __syncthreads();
    }
  }
}

// ---------------------------------------------------------------------------
// K2c: per-batch scan. Prologue applies fixup combine; then lengths, hb bits,
// parallel prefix scan, segment starts, shortened mask, binomial NLL.
// ---------------------------------------------------------------------------
__global__ __launch_bounds__(256) void k2c_scan(
    float* __restrict__ logits,          // [8][2048] (fixed in-place)
    const float* __restrict__ mask,      // [8][2048]
    const float* __restrict__ target,    // [8]
    const float* __restrict__ b2,
    const float* __restrict__ fixpart,   // [MAXFLAG][8]
    const int* __restrict__ flaglist,
    const int* __restrict__ flagcnt,
    float* __restrict__ outmask,         // [8][2048]
    int*   __restrict__ seg,             // [8][2050]
    float* __restrict__ hdr)             // [8][4]
{
  const int b = blockIdx.x, tid = threadIdx.x;
  __shared__ float redf[256];
  __shared__ int tsum[256];
  __shared__ unsigned char hbs[L_];

  const int cnt = min(*flagcnt, MAXFLAG);
  for (int f = tid; f < cnt; f += 256) {
    const int i = flaglist[f];
    if ((i >> 11) == b) {
      float s = b2[0];
#pragma unroll
      for (int cg = 0; cg < 8; ++cg) s += fixpart[f * 8 + cg];
      logits[i] = s;
    }
  }
  float lm = 0.f;
#pragma unroll
  for (int e = 0; e < 8; ++e) lm += mask[b * L_ + tid * 8 + e];
  redf[tid] = lm;
  __syncthreads();
  for (int s = 128; s > 0; s >>= 1) {
    if (tid < s) redf[tid] += redf[tid + s];
    __syncthreads();
  }
  const int length = (int)(redf[0] + 0.5f);

  int hloc[8];
  int lsum = 0;
#pragma unroll
  for (int e = 0; e < 8; ++e) {
    const int t = tid * 8 + e;
    const float lg = logits[b * L_ + t];
    int hb = (lg > 0.f) && (t < length);
    if (length < L_ && t == length - 1) hb = 1;
    hloc[e] = hb;
    hbs[t] = (unsigned char)hb;
    lsum += hb;
  }
  tsum[tid] = lsum;
  __syncthreads();
  for (int off = 1; off < 256; off <<= 1) {
    int v = tsum[tid];
    int add = (tid >= off) ? tsum[tid - off] : 0;
    __syncthreads();
    tsum[tid] = v + add;
    __syncthreads();
  }
  const int ktot = tsum[255];

  int pre = tsum[tid] - lsum;            // exclusive prefix
  for (int e = 0; e < 8; ++e) {
    const int t = tid * 8 + e;
    if (t < length) {
      const bool st = (t == 0) || hbs[t - 1];
      if (st) seg[b * 2050 + pre] = t;
    }
    pre += hloc[e];
  }

#pragma unroll
  for (int e = 0; e < 8; ++e) {
    const int t = tid * 8 + e;
    outmask[b * L_ + t] = (t < ktot) ? 1.f : 0.f;
  }

  __syncthreads();
  if (tid == 0) {
    const int maxseg = ktot - (length > 0 ? (int)hbs[length - 1] : 0);
    seg[b * 2050 + maxseg + 1] = length;
    const float n = (float)length, k = (float)ktot;
    float p = target[b] / fmaxf(n, 1.f);
    p = fminf(fmaxf(p, 1e-6f), 1.f - 1e-6f);
    const float lp = lgammaf(n + 1.f) - lgammaf(k + 1.f) - lgammaf(n - k + 1.f)
                   + k * logf(p) + (n - k) * log1pf(-p);
    hdr[b * 4 + 0] = n;
    hdr[b * 4 + 1] = k;
    hdr[b * 4 + 2] = (float)maxseg;
    hdr[b * 4 + 3] = -lp;
  }
}

// ---------------------------------------------------------------------------
// K4b: pooled[b][s][:] = mean(hidden[b][st:en][:]) + PE[s][:]
// PE frequencies from LUT (k2a) -> no per-thread exp2f.
// ---------------------------------------------------------------------------
__global__ __launch_bounds__(256) void k4b_pool(
    const float* __restrict__ hidden,
    const float* __restrict__ chunkSum,
    const int*   __restrict__ seg,
    const float* __restrict__ hdr,
    const float* __restrict__ freq,      // [512]
    float* __restrict__ pooled,
    float* __restrict__ out3)
{
  const int bid = blockIdx.x;
  const int b = bid >> 11, s = bid & 2047;
  const int tid = threadIdx.x;
  if (bid == 0 && tid == 0) {
    float s_lp = 0.f, s_k = 0.f, s_n = 0.f;
    for (int i = 0; i < B_; ++i) {
      s_n  += hdr[i * 4 + 0];
      s_k  += hdr[i * 4 + 1];
      s_lp += hdr[i * 4 + 3];
    }
    out3[0] = 10.f * (s_lp * 0.125f);
    out3[1] = s_k;
    out3[2] = s_n;
  }
  const int maxseg = (int)hdr[b * 4 + 2];

  float a0 = 0.f, a1 = 0.f, a2 = 0.f, a3 = 0.f;
  if (s <= maxseg) {
    const int st = seg[b * 2050 + s];
    const int en = seg[b * 2050 + s + 1];
    const float* hrow = hidden + (size_t)(b * L_) * D_ + tid * 4;
    const float* crow = chunkSum + (size_t)(b * NCH) * D_ + tid * 4;
    const int cs = (st + CHK - 1) / CHK;
    const int ce = en / CHK;
    if (cs >= ce) {
      for (int t = st; t < en; ++t) {
        const f32x4_t v = *(const f32x4_t*)(hrow + (size_t)t * D_);
        a0 += v.x; a1 += v.y; a2 += v.z; a3 += v.w;
      }
    } else {
      for (int t = st; t < cs * CHK; ++t) {
        const f32x4_t v = *(const f32x4_t*)(hrow + (size_t)t * D_);
        a0 += v.x; a1 += v.y; a2 += v.z; a3 += v.w;
      }
#pragma unroll 4
      for (int c = cs; c < ce; ++c) {
        const f32x4_t v = *(const f32x4_t*)(crow + (size_t)c * D_);
        a0 += v.x; a1 += v.y; a2 += v.z; a3 += v.w;
      }
      for (int t = ce * CHK; t < en; ++t) {
        const f32x4_t v = *(const f32x4_t*)(hrow + (size_t)t * D_);
        a0 += v.x; a1 += v.y; a2 += v.z; a3 += v.w;
      }
    }
    const float cnt = (float)(en - st);
    const float inv = 1.f / (cnt + 1e-9f);
    a0 *= inv; a1 *= inv; a2 *= inv; a3 *= inv;
  }
  const f32x2_t f = *(const f32x2_t*)(freq + 2 * tid);
  const float ang0 = (float)s * f.x;
  const float ang1 = (float)s * f.y;
  float s0, c0, s1, c1;
  __sincosf(ang0, &s0, &c0);
  __sincosf(ang1, &s1, &c1);
  f32x4_t o;
  o.x = a0 + s0; o.y = a1 + c0; o.z = a2 + s1; o.w = a3 + c1;
  *(f32x4_t*)(pooled + ((size_t)(b * L_ + s)) * D_ + tid * 4) = o;
}

// ---------------------------------------------------------------------------
extern "C" void kernel_launch(void* const* d_in, const int* in_sizes, int n_in,
                              void* d_out, int out_size, void* d_ws, size_t ws_size,
                              hipStream_t stream)
{
  (void)in_sizes; (void)n_in; (void)out_size; (void)ws_size;
  const float* hidden = (const float*)d_in[0];
  const float* amask  = (const float*)d_in[1];
  const float* target = (const float*)d_in[2];
  const float* W1     = (const float*)d_in[3];
  const float* b1     = (const float*)d_in[4];
  const float* W2     = (const float*)d_in[5];
  const float* b2     = (const float*)d_in[6];

  float* out     = (float*)d_out;
  float* pooled  = out;                       // 16777216 floats (written LAST)
  float* out3    = out + 16777216;
  float* outmask = out + 16777219;

  // Abf (16MB) + Bbf (2MB) live inside the pooled output region as scratch;
  // k4b fully overwrites pooled afterwards.
  unsigned char* Abf = (unsigned char*)out;               // 16 MB
  unsigned char* Bbf = (unsigned char*)(out + 8388608);   // 2 MB at byte offset 32MB

  char* ws = (char*)d_ws;
  float* partial  = (float*)ws;                      ws += (size_t)16384 * NBLK * 4;  // 512 KB
  int*   seg      = (int*)ws;                        ws += (size_t)B_ * 2050 * 4;
  float* hdr      = (float*)ws;                      ws += (size_t)B_ * 4 * 4;
  float* logits   = (float*)ws;                      ws += (size_t)B_ * L_ * 4;       // 64 KB
  int*   flaglist = (int*)ws;                        ws += (size_t)MAXFLAG * 4;
  int*   flagcnt  = (int*)ws;                        ws += 256;
  float* fixpart  = (float*)ws;                      ws += (size_t)MAXFLAG * 8 * 4;   // 32 KB
  float* freq     = (float*)ws;                      ws += 512 * 4;                   // 2 KB
  float* chunkSum = (float*)ws;                      // 2 MB

  k0_pack<<<dim3(NK, 72), dim3(256), 0, stream>>>(hidden, W1, Abf, Bbf,
                                                  chunkSum, flagcnt);
  k1_gemm<<<dim3(512), dim3(512), 131072, stream>>>(Abf, Bbf, b1, W2, partial);
  k2a_logits<<<dim3(64), dim3(256), 0, stream>>>(partial, b2, logits, flaglist,
                                                 flagcnt, freq);
  k2b_fixup<<<dim3(8, 16), dim3(256), 0, stream>>>(hidden, W1, b1, W2,
                                                   flaglist, flagcnt, fixpart);
  k2c_scan<<<dim3(8), dim3(256), 0, stream>>>(logits, amask, target, b2, fixpart,
                                              flaglist, flagcnt, outmask, seg, hdr);
  k4b_pool<<<dim3(16384), dim3(256), 0, stream>>>(hidden, chunkSum, seg, hdr,
                                                  freq, pooled, out3);
}